// Round 9
// baseline (463.901 us; speedup 1.0000x reference)
//
#include <hip/hip_runtime.h>
#include <hip/hip_bf16.h>
#include <cstdint>

// ---------------------------------------------------------------------------
// LinearAttention on MI355X (gfx950)
// L=4096, N=4, E=1024, H=16, D=64.  M = L*N = 16384.
// Round 13: un-bundle R8. Revert (a) convert_x3 and (b) gemm_bt3 (timed
// regression traced to warm-L3 eviction: batching breaks the interleaved
// convert->gemm producer-consumer locality that keeps A-tiles L3-hot).
// Keep only (c): kv_reduce builds the swizzled bf16 hi/lo B-image once per
// head-group (20480 B, byte-identical to attn_out's LDS B buffer; validated
// in R8, absmax unchanged); attn_out stages it with 5 linear global_load_lds
// instead of a 16x-redundant per-block reduce+convert+scatter.
// Everything else identical to R7 (best measured: 453.5 us).
// ---------------------------------------------------------------------------

typedef __attribute__((ext_vector_type(8))) short bf16x8;
typedef __attribute__((ext_vector_type(4))) float f32x4;

#define L_SEQ 4096
#define NBATCH 4
#define EMB 1024
#define NHEADS 16
#define HDIM 64
#define MROWS (L_SEQ * NBATCH)   // 16384
#define NHG (NBATCH * NHEADS)    // 64 head-groups
#define LCHUNK 512
#define NCHUNK (L_SEQ / LCHUNK)  // 8
#define KVB_SH 10240             // shorts per hg in kvB image (20480 B)

__device__ __forceinline__ unsigned short f2bf(float f) {
  union { float f; uint32_t u; } v; v.f = f;
  uint32_t u = v.u;
  u += 0x7fffu + ((u >> 16) & 1u);   // round-to-nearest-even
  return (unsigned short)(u >> 16);
}
__device__ __forceinline__ float bf2f(unsigned short s) {
  union { uint32_t u; float f; } v; v.u = ((uint32_t)s) << 16;
  return v.f;
}
__device__ __forceinline__ uint32_t pkbf(float a, float b) {
  union { float f; uint32_t u; } ua, ub; ua.f = a; ub.f = b;
  return ((ua.u + 0x8000u) >> 16) | ((ub.u + 0x8000u) & 0xffff0000u);
}

// ---------------- fp32 -> bf16 convert ---------------------------------------
__global__ __launch_bounds__(256) void convert_kernel(const float* __restrict__ src,
                                                      unsigned short* __restrict__ dst,
                                                      int n) {
  int i = (blockIdx.x * 256 + threadIdx.x) * 4;
  if (i + 4 <= n) {
    float4 f = *(const float4*)(src + i);
    uint2 p;
    p.x = pkbf(f.x, f.y);
    p.y = pkbf(f.z, f.w);
    *(uint2*)(dst + i) = p;
  }
}

// ---------------- fp32 -> bf16 convert, 4 weight matrices -------------------
__global__ __launch_bounds__(256) void convert_w4(const float* __restrict__ s0,
                                                  const float* __restrict__ s1,
                                                  const float* __restrict__ s2,
                                                  const float* __restrict__ s3,
                                                  unsigned short* __restrict__ d0,
                                                  unsigned short* __restrict__ d1,
                                                  unsigned short* __restrict__ d2,
                                                  unsigned short* __restrict__ d3,
                                                  int n) {
  const int w = blockIdx.y;
  const float* src = (w == 0) ? s0 : (w == 1) ? s1 : (w == 2) ? s2 : s3;
  unsigned short* dst = (w == 0) ? d0 : (w == 1) ? d1 : (w == 2) ? d2 : d3;
  int i = (blockIdx.x * 256 + threadIdx.x) * 4;
  if (i + 4 <= n) {
    float4 f = *(const float4*)(src + i);
    uint2 p;
    p.x = pkbf(f.x, f.y);
    p.y = pkbf(f.z, f.w);
    *(uint2*)(dst + i) = p;
  }
}

// ---------------- bf16 MFMA GEMM: C = A(MxK) . B(NnxK)^T + bias -------------
// MODE 0: elu(x)+1 -> bf16 ; MODE 1: x -> bf16 ; MODE 2: x -> fp32
// M % 256 == 0, Nn % 256 == 0, K % 128 == 0 (NT = K/64 even, >= 4).
// 512 threads (8 waves: wr = wid>>2 in {0,1} -> M; wc = wid&3 -> N).
// LDS: A half-slots s*16384 (s=0..3), B half-slots 65536 + s*16384 (128 KB).
// Half-tile (128 rows x 64 k) of tile u, half h lives in slot (2u+h)&3.
// Swizzle: within a 128 B row, byte ^= ((row&7)<<4) (involution; applied to
// the gload_lds GLOBAL source and to ds_read addresses; LDS dest stays linear).

// stage one 128x64 half-tile: MATB 0=A/1=B, RH row-half, SLOT, KTN k-offset.
#define STAGE_H(MATB, RH, SLOT, KTN)                                            \
  do {                                                                          \
    _Pragma("unroll")                                                           \
    for (int r_ = 0; r_ < 2; r_++) {                                            \
      const long grow_ = ((MATB) ? bcol0 : arow0) + (RH) * 128 + r_ * 64 + srowt;\
      const unsigned short* gp_ =                                               \
          ((MATB) ? B : A) + grow_ * (long)K + (KTN) + skoff;                   \
      __builtin_amdgcn_global_load_lds(                                         \
          (const __attribute__((address_space(1))) void*)gp_,                   \
          (__attribute__((address_space(3))) void*)(smem + (MATB) * 65536 +     \
              (SLOT) * 16384 + r_ * 8192 + wid * 1024),                         \
          16, 0, 0);                                                            \
    }                                                                           \
  } while (0)

// one 16-MFMA cluster: C quadrant rows MFB..MFB+3 x cols NFB..NFB+1, K=64
#define MFMA_Q(AF, BF, MFB, NFB)                                                \
  do {                                                                          \
    __builtin_amdgcn_s_setprio(1);                                              \
    _Pragma("unroll")                                                           \
    for (int mi_ = 0; mi_ < 4; mi_++)                                           \
      _Pragma("unroll")                                                         \
      for (int ni_ = 0; ni_ < 2; ni_++)                                         \
        _Pragma("unroll")                                                       \
        for (int ks_ = 0; ks_ < 2; ks_++)                                       \
          acc[(MFB) + mi_][(NFB) + ni_] =                                       \
              __builtin_amdgcn_mfma_f32_16x16x32_bf16(                          \
                  AF[mi_ * 2 + ks_], BF[ni_ * 2 + ks_],                         \
                  acc[(MFB) + mi_][(NFB) + ni_], 0, 0, 0);                      \
    __builtin_amdgcn_s_setprio(0);                                              \
  } while (0)

#define PH_SYNC                                                                 \
  __builtin_amdgcn_s_barrier();                                                 \
  asm volatile("s_waitcnt lgkmcnt(0)" ::: "memory");                            \
  __builtin_amdgcn_sched_barrier(0);

// one K-tile u (A/B lo slots at SA, hi at SA+1; SA in {0,2} = (2u)&3).
// Stages: ph0 A-hi(u+1)->slot SA^3 (iff S01), ph1 B-hi(u+1)->SA^3 (iff S01),
//         ph2 B-lo(u+2)->SA (iff S23),        ph3 A-lo(u+2)->SA (iff S23).
// VMODE: 1 = boundary vmcnt(4) (steady), 2 = vmcnt(0) (tail fill), 0 = none.
#define TILE_T(SA, K1, K2, S01, S23, VMODE)                                     \
  do {                                                                          \
    bf16x8 af0[8], af1[8], bf0[4], bf1[4];                                      \
    /* ph0: read A rows 0-63 of half wr + B rows lo; stage A-hi(u+1) */         \
    _Pragma("unroll")                                                           \
    for (int mi_ = 0; mi_ < 4; mi_++)                                           \
      _Pragma("unroll")                                                         \
      for (int ks_ = 0; ks_ < 2; ks_++)                                         \
        af0[mi_ * 2 + ks_] = *(const bf16x8*)(smem + ((SA) + wr) * 16384 + aRB +\
                                              mi_ * 2048 + akt[ks_]);           \
    _Pragma("unroll")                                                           \
    for (int ni_ = 0; ni_ < 2; ni_++)                                           \
      _Pragma("unroll")                                                         \
      for (int ks_ = 0; ks_ < 2; ks_++)                                         \
        bf0[ni_ * 2 + ks_] = *(const bf16x8*)(smem + 65536 +                    \
                                              ((SA) + (wc >> 1)) * 16384 + bRB +\
                                              ni_ * 2048 + akt[ks_]);           \
    if (S01) STAGE_H(0, 1, (SA) ^ 3, K1);                                       \
    PH_SYNC                                                                     \
    MFMA_Q(af0, bf0, 0, 0);                                                     \
    __builtin_amdgcn_s_barrier();                                               \
    /* ph1: read B rows hi; stage B-hi(u+1) */                                  \
    _Pragma("unroll")                                                           \
    for (int ni_ = 0; ni_ < 2; ni_++)                                           \
      _Pragma("unroll")                                                         \
      for (int ks_ = 0; ks_ < 2; ks_++)                                         \
        bf1[ni_ * 2 + ks_] = *(const bf16x8*)(smem + 65536 +                    \
                                              ((SA) + (wc >> 1)) * 16384 + bRB +\
                                              (ni_ + 2) * 2048 + akt[ks_]);     \
    if (S01) STAGE_H(1, 1, (SA) ^ 3, K1);                                       \
    PH_SYNC                                                                     \
    MFMA_Q(af0, bf1, 0, 2);                                                     \
    __builtin_amdgcn_s_barrier();                                               \
    /* ph2: read A rows 64-127; stage B-lo(u+2) */                              \
    _Pragma("unroll")                                                           \
    for (int mi_ = 0; mi_ < 4; mi_++)                                           \
      _Pragma("unroll")                                                         \
      for (int ks_ = 0; ks_ < 2; ks_++)                                         \
        af1[mi_ * 2 + ks_] = *(const bf16x8*)(smem + ((SA) + wr) * 16384 + aRB +\
                                              (mi_ + 4) * 2048 + akt[ks_]);     \
    if (S23) STAGE_H(1, 0, (SA), K2);                                           \
    PH_SYNC                                                                     \
    MFMA_Q(af1, bf1, 4, 2);                                                     \
    __builtin_amdgcn_s_barrier();                                               \
    /* ph3: no reads; stage A-lo(u+2); counted boundary wait */                 \
    if (S23) STAGE_H(0, 0, (SA), K2);                                           \
    PH_SYNC                                                                     \
    MFMA_Q(af1, bf0, 4, 0);                                                     \
    if ((VMODE) == 1) asm volatile("s_waitcnt vmcnt(4)" ::: "memory");          \
    if ((VMODE) == 2) asm volatile("s_waitcnt vmcnt(0)" ::: "memory");          \
    __builtin_amdgcn_s_barrier();                                               \
  } while (0)

template <int MODE>
__global__ __launch_bounds__(512, 2) void gemm_bt(const unsigned short* __restrict__ A,
                                                  const unsigned short* __restrict__ B,
                                                  const float* __restrict__ bias,
                                                  void* __restrict__ Cout,
                                                  int M, int Nn, int K) {
  __shared__ __align__(16) char smem[131072];

  const int tid   = threadIdx.x;
  const int wid   = tid >> 6;
  const int lane  = tid & 63;
  const int col16 = lane & 15;
  const int quad  = lane >> 4;
  const int wr = wid >> 2;       // 0..1 : M half (rows wr*128..+127)
  const int wc = wid & 3;        // 0..3 : N quarter (cols wc*64..+63)
  const long arow0 = (long)blockIdx.x * 256;
  const long bcol0 = (long)blockIdx.y * 256;

  // ---- read-address constants (swizzled) ----
  const int axor = (col16 & 7) << 4;
  int akt[2];
  akt[0] = (quad * 16) ^ axor;
  akt[1] = (64 + quad * 16) ^ axor;
  const int aRB = col16 * 128;                    // within-slot A row base
  const int bRB = ((wc & 1) * 64 + col16) * 128;  // within-slot B row base

  // ---- staging constants (inverse-swizzled global source) ----
  const int srowt = tid >> 3;                                   // 0..63
  const int skoff = (((tid & 7) * 16) ^ ((srowt & 7) << 4)) >> 1;  // shorts

  const int NT = K >> 6;   // K-tiles of 64 (even, >= 4)

  // prologue: tile0 all 4 halves + B-lo(1) + A-lo(1)  (6 stage-ops, 12 loads)
  STAGE_H(0, 0, 0, 0);      // A-lo(0) -> A-slot0
  STAGE_H(0, 1, 1, 0);      // A-hi(0) -> A-slot1
  STAGE_H(1, 0, 0, 0);      // B-lo(0) -> B-slot0
  STAGE_H(1, 1, 1, 0);      // B-hi(0) -> B-slot1
  STAGE_H(1, 0, 2, 64);     // B-lo(1) -> B-slot2
  STAGE_H(0, 0, 2, 64);     // A-lo(1) -> A-slot2

  const f32x4 fzero = {0.f, 0.f, 0.f, 0.f};
  f32x4 acc[8][4];
#pragma unroll
  for (int i = 0; i < 8; i++)
#pragma unroll
    for (int j = 0; j < 4; j++) acc[i][j] = fzero;

  asm volatile("s_waitcnt vmcnt(4)" ::: "memory");  // tile 0 resident
  __builtin_amdgcn_s_barrier();

  // main loop: full-stage tiles 0..NT-3 in pairs
#pragma unroll 1
  for (int u = 0; u + 4 <= NT; u += 2) {
    TILE_T(0, (u + 1) * 64, (u + 2) * 64, 1, 1, 1);
    TILE_T(2, (u + 2) * 64, (u + 3) * 64, 1, 1, 1);
  }
  // tail: tile NT-2 stages only hi-halves of NT-1; tile NT-1 stages nothing
  TILE_T(0, (NT - 1) * 64, 0, 1, 0, 2);
  TILE_T(2, 0, 0, 0, 0, 0);

  // ---- epilogue: 8 slabs of 32 rows x 256 cols through LDS ----
  // C/D frag: row = quad*4 + rr, col = col16 (verified layout).
  float bcol[4];
#pragma unroll
  for (int nf = 0; nf < 4; nf++) bcol[nf] = bias[bcol0 + wc * 64 + nf * 16 + col16];

  const int erow = tid >> 4;   // 0..31
  const int ecc  = tid & 15;   // 16-col chunk

  if (MODE != 2) {
    unsigned short* epi = (unsigned short*)smem;
    const int EST = 264;  // shorts; 528 B row stride (16B-aligned, bank-skewed)
#pragma unroll
    for (int s = 0; s < 8; s++) {
      if ((s >> 2) == wr) {
        const int mfb = (s & 3) * 2;
#pragma unroll
        for (int ml = 0; ml < 2; ml++)
#pragma unroll
          for (int nf = 0; nf < 4; nf++)
#pragma unroll
            for (int rr = 0; rr < 4; rr++) {
              float vv = acc[mfb + ml][nf][rr] + bcol[nf];
              if (MODE == 0) vv = (vv > 0.f) ? (vv + 1.f) : __expf(vv);  // elu+1
              epi[(ml * 16 + quad * 4 + rr) * EST + wc * 64 + nf * 16 + col16] =
                  f2bf(vv);
            }
      }
      __syncthreads();
      {
        const long gr = arow0 + s * 32 + erow;
        const unsigned short* srcp = &epi[erow * EST + ecc * 16];
        uint4 a  = *(const uint4*)srcp;
        uint4 b2 = *(const uint4*)(srcp + 8);
        unsigned short* Cp = (unsigned short*)Cout + gr * Nn + bcol0 + ecc * 16;
        *(uint4*)Cp       = a;
        *(uint4*)(Cp + 8) = b2;
      }
      __syncthreads();
    }
  } else {
    float* epi = (float*)smem;
    const int ESF = 260;  // floats; 1040 B row stride (16B-aligned, bank-skewed)
#pragma unroll
    for (int s = 0; s < 8; s++) {
      if ((s >> 2) == wr) {
        const int mfb = (s & 3) * 2;
#pragma unroll
        for (int ml = 0; ml < 2; ml++)
#pragma unroll
          for (int nf = 0; nf < 4; nf++)
#pragma unroll
            for (int rr = 0; rr < 4; rr++)
              epi[(ml * 16 + quad * 4 + rr) * ESF + wc * 64 + nf * 16 + col16] =
                  acc[mfb + ml][nf][rr] + bcol[nf];
      }
      __syncthreads();
      {
        const long gr = arow0 + s * 32 + erow;
        const float* srcp = &epi[erow * ESF + ecc * 16];
        float* Cp = (float*)Cout + gr * Nn + bcol0 + ecc * 16;
#pragma unroll
        for (int s4 = 0; s4 < 4; s4++)
          *(float4*)(Cp + s4 * 4) = *(const float4*)(srcp + s4 * 4);
      }
      __syncthreads();
    }
  }
}

// ---------------- kv partials: kv[d][e] = sum_l kf[l][d]*v[l][e] ------------
// grid (NHG, NCHUNK), block 256. Non-atomic partial outputs per chunk.
__global__ __launch_bounds__(256) void kv_partial_kernel(const unsigned short* __restrict__ kf,
                                                         const unsigned short* __restrict__ vp,
                                                         float* __restrict__ kvp,
                                                         float* __restrict__ ksp) {
  __shared__ float ks[32 * 64];
  __shared__ float vs[32 * 64];
  const int hg = blockIdx.x;
  const int chunk = blockIdx.y;
  const int n = hg >> 4, h = hg & 15;
  const int tid = threadIdx.x;
  const int td = tid >> 4, te = tid & 15;   // thread covers d=td*4..+3, e=te*4..+3
  const long hoff = (long)n * EMB + h * HDIM;
  const int l0 = chunk * LCHUNK;

  float acc[4][4];
#pragma unroll
  for (int i = 0; i < 4; i++)
#pragma unroll
    for (int j = 0; j < 4; j++) acc[i][j] = 0.f;
  float ksacc[4] = {0.f, 0.f, 0.f, 0.f};

  const int lrow = tid >> 3;         // 0..31
  const int dcol = (tid & 7) * 8;    // 0..56

  for (int ls = 0; ls < LCHUNK; ls += 32) {
    const long g = (long)(l0 + ls + lrow) * (NBATCH * EMB) + hoff + dcol;
    uint4 kr = *(const uint4*)(kf + g);
    uint4 vr = *(const uint4*)(vp + g);
    float* kd = &ks[lrow * 64 + dcol];
    float* vd = &vs[lrow * 64 + dcol];
    uint32_t ku[4] = {kr.x, kr.y, kr.z, kr.w};
    uint32_t vu[4] = {vr.x, vr.y, vr.z, vr.w};
#pragma unroll
    for (int t2 = 0; t2 < 4; t2++) {
      kd[2 * t2]     = bf2f((unsigned short)(ku[t2] & 0xffffu));
      kd[2 * t2 + 1] = bf2f((unsigned short)(ku[t2] >> 16));
      vd[2 * t2]     = bf2f((unsigned short)(vu[t2] & 0xffffu));
      vd[2 * t2 + 1] = bf2f((unsigned short)(vu[t2] >> 16));
    }
    __syncthreads();
#pragma unroll
    for (int l = 0; l < 32; l++) {
      float kq[4], vq[4];
      *(float4*)kq = *(const float4*)(&ks[l * 64 + td * 4]);
      *(float4*)vq = *(const float4*)(&vs[l * 64 + te * 4]);
#pragma unroll
      for (int i = 0; i < 4; i++) {
        ksacc[i] += kq[i];
#pragma unroll
        for (int j = 0; j < 4; j++) acc[i][j] += kq[i] * vq[j];
      }
    }
    __syncthreads();
  }
  float* outp = kvp + ((long)chunk * NHG + hg) * 4096;
#pragma unroll
  for (int i = 0; i < 4; i++)
#pragma unroll
    for (int j = 0; j < 4; j++)
      outp[(td * 4 + i) * 64 + te * 4 + j] = acc[i][j];
  if (te == 0) {
    float* o2 = ksp + ((long)chunk * NHG + hg) * 64;
#pragma unroll
    for (int i = 0; i < 4; i++) o2[td * 4 + i] = ksacc[i];
  }
}

// ---------------- kv_reduce: build swizzled bf16 hi/lo B-image per hg -------
// grid NHG, block 256. Output: kvB[hg][20480 B] =
//   rows 0..63 (e): k 0..63 = kv_hi^T, 64..127 = kv_lo^T (swizzled);
//   row 64: ksum hi/lo; rows 65..79: zero. Identical byte layout to the
//   LDS B buffer attn_out consumes (linear copy via global_load_lds there).
__global__ __launch_bounds__(256) void kv_reduce(const float* __restrict__ kvp,
                                                 const float* __restrict__ ksp,
                                                 unsigned short* __restrict__ kvB) {
  const int hg = blockIdx.x;
  const int tid = threadIdx.x;
  unsigned short* gB = kvB + (long)hg * KVB_SH;

  for (int wb = tid * 4; wb < 4096; wb += 1024) {
    float4 s = make_float4(0.f, 0.f, 0.f, 0.f);
#pragma unroll
    for (int c = 0; c < NCHUNK; c++) {
      const float4 t = *(const float4*)(kvp + ((long)c * NHG + hg) * 4096 + wb);
      s.x += t.x; s.y += t.y; s.z += t.z; s.w += t.w;
    }
    const int d = wb >> 6;
    const int e0 = wb & 63;
    float sv[4] = {s.x, s.y, s.z, s.w};
#pragma unroll
    for (int j = 0; j < 4; j++) {
      const int e = e0 + j;
      const unsigned short hi = f2bf(sv[j]);
      const unsigned short lo = f2bf(sv[j] - bf2f(hi));
      const int key = (e & 7) << 4;
      gB[(e * 256 + ((2 * d) ^ key)) >> 1]       = hi;
      gB[(e * 256 + ((128 + 2 * d) ^ key)) >> 1] = lo;
    }
  }
  if (tid < 64) {
    float s = 0.f;
#pragma unroll
    for (int c = 0; c < NCHUNK; c++) s += ksp[((long)c * NHG + hg) * 64 + tid];
    const unsigned short hi = f2bf(s);
    const unsigned short lo = f2bf(s - bf2f(hi));
    gB[(64 * 256 + 2 * tid) >> 1]       = hi;   // row 64: key=0
    gB[(64 * 256 + 128 + 2 * tid) >> 1] = lo;
  }
  {  // zero rows 65..79
    uint32_t* zb = (uint32_t*)(gB + 65 * 128);
    for (int i = tid; i < 15 * 64; i += 256) zb[i] = 0u;
  }
}

// ---------------- out1 = (qf @ kv) * 1/(qf.ksum + eps), bf16 row-major ------
// grid (NHG, 16), block 256 (4 waves). MFMA; B staged as linear copy of the
// precomputed kvB image (5 global_load_lds), qf staged swizzled (8).
__global__ __launch_bounds__(256) void attn_out_kernel(const unsigned short* __restrict__ qf,
                                                       const unsigned short* __restrict__ kvB,
                                                       unsigned short* __restrict__ out1) {
  __shared__ __align__(16) char smem[53248];
  const int hg = blockIdx.x;
  const int lc = blockIdx.y;
  const int n = hg >> 4, h = hg & 15;
  const int tid = threadIdx.x;
  const int wid = tid >> 6;
  const int lane = tid & 63;
  const int col16 = lane & 15;
  const int quad  = lane >> 4;
  const long lbase = (long)lc * 256;

  // ---- stage A = qf[lbase..+255][h*64..+63] via gload_lds (swizzled source)
#pragma unroll
  for (int r = 0; r < 8; r++) {
    const int row = r * 32 + (tid >> 3);
    const long l = lbase + row;
    const int sk = (((tid & 7) * 16) ^ ((row & 7) << 4)) >> 1;   // shorts
    const unsigned short* gp = qf + (l * NBATCH + n) * (long)EMB + h * HDIM + sk;
    __builtin_amdgcn_global_load_lds(
        (const __attribute__((address_space(1))) void*)gp,
        (__attribute__((address_space(3))) void*)(smem + r * 4096 + tid * 16),
        16, 0, 0);
  }
  // ---- stage B: linear copy of the 20480-B kvB image
  {
    const unsigned short* gB = kvB + (long)hg * KVB_SH;
#pragma unroll
    for (int r = 0; r < 5; r++) {
      __builtin_amdgcn_global_load_lds(
          (const __attribute__((address_space(1))) void*)(gB + r * 2048 + tid * 8),
          (__attribute__((address_space(3))) void*)(smem + 32768 + r * 4096 + tid * 16),
          16, 0, 0);
    }
  }
  __syncthreads();

  char* Bl = smem + 32768;
  // ---- MFMA: per wave 64 l-rows x 80 cols, logical K=128 (hi pass + lo pass)
  const int wl0 = wid * 64;
  const int akey = (col16 & 7) << 4;

  bf16x8 af[4][2];
#pragma unroll
  for (int mi = 0; mi < 4; mi++)
#pragma unroll
    for (int ks = 0; ks < 2; ks++)
      af[mi][ks] = *(const bf16x8*)(smem + (wl0 + mi * 16 + col16) * 128 +
                                    ((ks * 64 + quad * 16) ^ akey));

  const f32x4 fzero = {0.f, 0.f, 0.f, 0.f};
  f32x4 acc[4][5];
#pragma unroll
  for (int mi = 0; mi < 4; mi++)
#pragma unroll
    for (int nf = 0; nf < 5; nf++) acc[mi][nf] = fzero;

#pragma unroll
  for (int nf = 0; nf < 5; nf++) {
    bf16x8 bfr[4];
#pragma unroll
    for (int pass = 0; pass < 2; pass++)
#pragma unroll
      for (int ks = 0; ks < 2; ks++)
        bfr[pass * 2 + ks] = *(const bf16x8*)(Bl + (nf * 16 + col16) * 256 +
                                              ((pass * 128 + ks * 64 + quad * 16) ^ akey));
#pragma unroll
    for (int mi = 0; mi < 4; mi++)
#pragma unroll
      for (int pass = 0; pass < 2; pass++)
#pragma unroll
        for (int ks = 0; ks < 2; ks++)
          acc[mi][nf] = __builtin_amdgcn_mfma_f32_16x16x32_bf16(
              af[mi][ks], bfr[pass * 2 + ks], acc[mi][nf], 0, 0, 0);
  }

  __syncthreads();   // all A reads done; reuse A region as epilogue buffer

  // ---- epilogue: z from denom col (lane quad*16 holds col 64), swizzled LDS
  unsigned short* epi = (unsigned short*)smem;
#pragma unroll
  for (int mi = 0; mi < 4; mi++) {
#pragma unroll
    for (int rr = 0; rr < 4; rr++) {
      const float dv = __shfl(acc[mi][4][rr], lane & 48);
      const float z = 1.f / (dv + 1e-6f);
      const int row = wl0 + mi * 16 + quad * 4 + rr;
      const int key = (row & 7) << 4;
#pragma unroll
      for (int nf = 0; nf < 4; nf++)
        *(unsigned short*)((char*)epi + row * 128 +
                           (((nf * 16 + col16) * 2) ^ key)) =
            f2bf(acc[mi][nf][rr] * z);
    }
  }
  __syncthreads();

  // packed readback: thread -> one row chunk of 16 B per pass, 8 passes
#pragma unroll
  for (int r = 0; r < 8; r++) {
    const int row = r * 32 + (tid >> 3);
    const long l = lbase + row;
    const uint4 vv = *(const uint4*)((char*)epi + row * 128 +
                                     (((tid & 7) * 16) ^ ((row & 7) << 4)));
    *(uint4*)(out1 + (l * NBATCH + n) * (long)EMB + h * HDIM + (tid & 7) * 8) = vv;
  }
}

// ---------------------------------------------------------------------------
extern "C" void kernel_launch(void* const* d_in, const int* in_sizes, int n_in,
                              void* d_out, int out_size, void* d_ws, size_t ws_size,
                              hipStream_t stream) {
  const float* q  = (const float*)d_in[0];
  const float* k  = (const float*)d_in[1];
  const float* v  = (const float*)d_in[2];
  const float* Wq = (const float*)d_in[3];
  const float* bq = (const float*)d_in[4];
  const float* Wk = (const float*)d_in[5];
  const float* bk = (const float*)d_in[6];
  const float* Wv = (const float*)d_in[7];
  const float* bv = (const float*)d_in[8];
  const float* Wo = (const float*)d_in[9];
  const float* bo = (const float*)d_in[10];

  char* ws = (char*)d_ws;
  const size_t BUF  = (size_t)MROWS * EMB * 2;          // 33,554,432 B
  const size_t WSZ  = 4 * (size_t)EMB * EMB * 2;        // 8,388,608 B
  const size_t KVPZ = (size_t)NCHUNK * NHG * 4096 * 4;  // 8,388,608 B
  const size_t KSPZ = (size_t)NCHUNK * NHG * 64 * 4;    // 131,072 B

  unsigned short* T0  = (unsigned short*)(ws);            // A-staging / out1
  unsigned short* qf  = (unsigned short*)(ws + BUF);
  unsigned short* kf  = (unsigned short*)(ws + 2 * BUF);
  unsigned short* vp  = (unsigned short*)(ws + 3 * BUF);
  unsigned short* Wqb = (unsigned short*)(ws + 4 * BUF);
  unsigned short* Wkb = Wqb + (size_t)EMB * EMB;
  unsigned short* Wvb = Wkb + (size_t)EMB * EMB;
  unsigned short* Wob = Wvb + (size_t)EMB * EMB;
  float* kvp = (float*)(ws + 4 * BUF + WSZ);
  float* ksp = (float*)(ws + 4 * BUF + WSZ + KVPZ);
  unsigned short* kvB = (unsigned short*)(ws + 4 * BUF + WSZ + KVPZ + KSPZ);

  const int nQKV = MROWS * EMB;     // 16,777,216
  const int nW   = EMB * EMB;       // 1,048,576

  // all 4 weight matrices -> bf16 in one dispatch
  convert_w4<<<dim3(nW / 1024, 4), 256, 0, stream>>>(Wq, Wk, Wv, Wo,
                                                     Wqb, Wkb, Wvb, Wob, nW);

  dim3 gg(MROWS / 256, EMB / 256), bb(512);

  // projections (T0 reused as bf16 A-staging between GEMMs; stream-ordered,
  // interleaved convert->gemm keeps each A-buffer L3-hot at its consumer)
  convert_kernel<<<nQKV / 1024, 256, 0, stream>>>(q, T0, nQKV);
  gemm_bt<0><<<gg, bb, 0, stream>>>(T0, Wqb, bq, qf, MROWS, EMB, EMB);
  convert_kernel<<<nQKV / 1024, 256, 0, stream>>>(k, T0, nQKV);
  gemm_bt<0><<<gg, bb, 0, stream>>>(T0, Wkb, bk, kf, MROWS, EMB, EMB);
  convert_kernel<<<nQKV / 1024, 256, 0, stream>>>(v, T0, nQKV);
  gemm_bt<1><<<gg, bb, 0, stream>>>(T0, Wvb, bv, vp, MROWS, EMB, EMB);

  // attention state + output (out1 -> T0)
  kv_partial_kernel<<<dim3(NHG, NCHUNK), 256, 0, stream>>>(kf, vp, kvp, ksp);
  kv_reduce<<<NHG, 256, 0, stream>>>(kvp, ksp, kvB);
  attn_out_kernel<<<dim3(NHG, L_SEQ / 256), 256, 0, stream>>>(qf, kvB, T0);

  // final projection -> fp32 output
  gemm_bt<2><<<gg, bb, 0, stream>>>(T0, Wob, bo, d_out, MROWS, EMB, EMB);
}

// Round 10
// 453.010 us; speedup vs baseline: 1.0240x; 1.0240x over previous
//
#include <hip/hip_runtime.h>
#include <hip/hip_bf16.h>
#include <cstdint>

// ---------------------------------------------------------------------------
// LinearAttention on MI355X (gfx950)
// L=4096, N=4, E=1024, H=16, D=64.  M = L*N = 16384.
// Round 14: EXACT revert to R7 (best measured: 453.5 us). R8/R9 experiments
// (batched dispatches, kv_reduce pre-pass) both measured +10 us: the
// "redundant" per-block kv reduce in attn_out is L2-resident and overlapped
// with MFMA across 1024 blocks, so hoisting it into a serial 64-block
// dispatch adds critical-path latency instead of saving work.
// Configuration: separate convert dispatches interleaved with projection
// GEMMs (keeps A-tiles L3-hot at their consumer); gemm_bt = 256x256 8-phase,
// 4 cycling half-tile slots, counted vmcnt(4) boundaries, T2 swizzle, T5
// setprio; attn_out = MFMA with inline float4 kvp reduce + hi/lo bf16 split.
// ---------------------------------------------------------------------------

typedef __attribute__((ext_vector_type(8))) short bf16x8;
typedef __attribute__((ext_vector_type(4))) float f32x4;

#define L_SEQ 4096
#define NBATCH 4
#define EMB 1024
#define NHEADS 16
#define HDIM 64
#define MROWS (L_SEQ * NBATCH)   // 16384
#define NHG (NBATCH * NHEADS)    // 64 head-groups
#define LCHUNK 512
#define NCHUNK (L_SEQ / LCHUNK)  // 8

__device__ __forceinline__ unsigned short f2bf(float f) {
  union { float f; uint32_t u; } v; v.f = f;
  uint32_t u = v.u;
  u += 0x7fffu + ((u >> 16) & 1u);   // round-to-nearest-even
  return (unsigned short)(u >> 16);
}
__device__ __forceinline__ float bf2f(unsigned short s) {
  union { uint32_t u; float f; } v; v.u = ((uint32_t)s) << 16;
  return v.f;
}
__device__ __forceinline__ uint32_t pkbf(float a, float b) {
  union { float f; uint32_t u; } ua, ub; ua.f = a; ub.f = b;
  return ((ua.u + 0x8000u) >> 16) | ((ub.u + 0x8000u) & 0xffff0000u);
}

// ---------------- fp32 -> bf16 convert ---------------------------------------
__global__ __launch_bounds__(256) void convert_kernel(const float* __restrict__ src,
                                                      unsigned short* __restrict__ dst,
                                                      int n) {
  int i = (blockIdx.x * 256 + threadIdx.x) * 4;
  if (i + 4 <= n) {
    float4 f = *(const float4*)(src + i);
    uint2 p;
    p.x = pkbf(f.x, f.y);
    p.y = pkbf(f.z, f.w);
    *(uint2*)(dst + i) = p;
  }
}

// ---------------- fp32 -> bf16 convert, 4 weight matrices -------------------
__global__ __launch_bounds__(256) void convert_w4(const float* __restrict__ s0,
                                                  const float* __restrict__ s1,
                                                  const float* __restrict__ s2,
                                                  const float* __restrict__ s3,
                                                  unsigned short* __restrict__ d0,
                                                  unsigned short* __restrict__ d1,
                                                  unsigned short* __restrict__ d2,
                                                  unsigned short* __restrict__ d3,
                                                  int n) {
  const int w = blockIdx.y;
  const float* src = (w == 0) ? s0 : (w == 1) ? s1 : (w == 2) ? s2 : s3;
  unsigned short* dst = (w == 0) ? d0 : (w == 1) ? d1 : (w == 2) ? d2 : d3;
  int i = (blockIdx.x * 256 + threadIdx.x) * 4;
  if (i + 4 <= n) {
    float4 f = *(const float4*)(src + i);
    uint2 p;
    p.x = pkbf(f.x, f.y);
    p.y = pkbf(f.z, f.w);
    *(uint2*)(dst + i) = p;
  }
}

// ---------------- bf16 MFMA GEMM: C = A(MxK) . B(NnxK)^T + bias -------------
// MODE 0: elu(x)+1 -> bf16 ; MODE 1: x -> bf16 ; MODE 2: x -> fp32
// M % 256 == 0, Nn % 256 == 0, K % 128 == 0 (NT = K/64 even, >= 4).
// 512 threads (8 waves: wr = wid>>2 in {0,1} -> M; wc = wid&3 -> N).
// LDS: A half-slots s*16384 (s=0..3), B half-slots 65536 + s*16384 (128 KB).
// Half-tile (128 rows x 64 k) of tile u, half h lives in slot (2u+h)&3.
// Swizzle: within a 128 B row, byte ^= ((row&7)<<4) (involution; applied to
// the gload_lds GLOBAL source and to ds_read addresses; LDS dest stays linear).

// stage one 128x64 half-tile: MATB 0=A/1=B, RH row-half, SLOT, KTN k-offset.
#define STAGE_H(MATB, RH, SLOT, KTN)                                            \
  do {                                                                          \
    _Pragma("unroll")                                                           \
    for (int r_ = 0; r_ < 2; r_++) {                                            \
      const long grow_ = ((MATB) ? bcol0 : arow0) + (RH) * 128 + r_ * 64 + srowt;\
      const unsigned short* gp_ =                                               \
          ((MATB) ? B : A) + grow_ * (long)K + (KTN) + skoff;                   \
      __builtin_amdgcn_global_load_lds(                                         \
          (const __attribute__((address_space(1))) void*)gp_,                   \
          (__attribute__((address_space(3))) void*)(smem + (MATB) * 65536 +     \
              (SLOT) * 16384 + r_ * 8192 + wid * 1024),                         \
          16, 0, 0);                                                            \
    }                                                                           \
  } while (0)

// one 16-MFMA cluster: C quadrant rows MFB..MFB+3 x cols NFB..NFB+1, K=64
#define MFMA_Q(AF, BF, MFB, NFB)                                                \
  do {                                                                          \
    __builtin_amdgcn_s_setprio(1);                                              \
    _Pragma("unroll")                                                           \
    for (int mi_ = 0; mi_ < 4; mi_++)                                           \
      _Pragma("unroll")                                                         \
      for (int ni_ = 0; ni_ < 2; ni_++)                                         \
        _Pragma("unroll")                                                       \
        for (int ks_ = 0; ks_ < 2; ks_++)                                       \
          acc[(MFB) + mi_][(NFB) + ni_] =                                       \
              __builtin_amdgcn_mfma_f32_16x16x32_bf16(                          \
                  AF[mi_ * 2 + ks_], BF[ni_ * 2 + ks_],                         \
                  acc[(MFB) + mi_][(NFB) + ni_], 0, 0, 0);                      \
    __builtin_amdgcn_s_setprio(0);                                              \
  } while (0)

#define PH_SYNC                                                                 \
  __builtin_amdgcn_s_barrier();                                                 \
  asm volatile("s_waitcnt lgkmcnt(0)" ::: "memory");                            \
  __builtin_amdgcn_sched_barrier(0);

// one K-tile u (A/B lo slots at SA, hi at SA+1; SA in {0,2} = (2u)&3).
// Stages: ph0 A-hi(u+1)->slot SA^3 (iff S01), ph1 B-hi(u+1)->SA^3 (iff S01),
//         ph2 B-lo(u+2)->SA (iff S23),        ph3 A-lo(u+2)->SA (iff S23).
// VMODE: 1 = boundary vmcnt(4) (steady), 2 = vmcnt(0) (tail fill), 0 = none.
#define TILE_T(SA, K1, K2, S01, S23, VMODE)                                     \
  do {                                                                          \
    bf16x8 af0[8], af1[8], bf0[4], bf1[4];                                      \
    /* ph0: read A rows 0-63 of half wr + B rows lo; stage A-hi(u+1) */         \
    _Pragma("unroll")                                                           \
    for (int mi_ = 0; mi_ < 4; mi_++)                                           \
      _Pragma("unroll")                                                         \
      for (int ks_ = 0; ks_ < 2; ks_++)                                         \
        af0[mi_ * 2 + ks_] = *(const bf16x8*)(smem + ((SA) + wr) * 16384 + aRB +\
                                              mi_ * 2048 + akt[ks_]);           \
    _Pragma("unroll")                                                           \
    for (int ni_ = 0; ni_ < 2; ni_++)                                           \
      _Pragma("unroll")                                                         \
      for (int ks_ = 0; ks_ < 2; ks_++)                                         \
        bf0[ni_ * 2 + ks_] = *(const bf16x8*)(smem + 65536 +                    \
                                              ((SA) + (wc >> 1)) * 16384 + bRB +\
                                              ni_ * 2048 + akt[ks_]);           \
    if (S01) STAGE_H(0, 1, (SA) ^ 3, K1);                                       \
    PH_SYNC                                                                     \
    MFMA_Q(af0, bf0, 0, 0);                                                     \
    __builtin_amdgcn_s_barrier();                                               \
    /* ph1: read B rows hi; stage B-hi(u+1) */                                  \
    _Pragma("unroll")                                                           \
    for (int ni_ = 0; ni_ < 2; ni_++)                                           \
      _Pragma("unroll")                                                         \
      for (int ks_ = 0; ks_ < 2; ks_++)                                         \
        bf1[ni_ * 2 + ks_] = *(const bf16x8*)(smem + 65536 +                    \
                                              ((SA) + (wc >> 1)) * 16384 + bRB +\
                                              (ni_ + 2) * 2048 + akt[ks_]);     \
    if (S01) STAGE_H(1, 1, (SA) ^ 3, K1);                                       \
    PH_SYNC                                                                     \
    MFMA_Q(af0, bf1, 0, 2);                                                     \
    __builtin_amdgcn_s_barrier();                                               \
    /* ph2: read A rows 64-127; stage B-lo(u+2) */                              \
    _Pragma("unroll")                                                           \
    for (int mi_ = 0; mi_ < 4; mi_++)                                           \
      _Pragma("unroll")                                                         \
      for (int ks_ = 0; ks_ < 2; ks_++)                                         \
        af1[mi_ * 2 + ks_] = *(const bf16x8*)(smem + ((SA) + wr) * 16384 + aRB +\
                                              (mi_ + 4) * 2048 + akt[ks_]);     \
    if (S23) STAGE_H(1, 0, (SA), K2);                                           \
    PH_SYNC                                                                     \
    MFMA_Q(af1, bf1, 4, 2);                                                     \
    __builtin_amdgcn_s_barrier();                                               \
    /* ph3: no reads; stage A-lo(u+2); counted boundary wait */                 \
    if (S23) STAGE_H(0, 0, (SA), K2);                                           \
    PH_SYNC                                                                     \
    MFMA_Q(af1, bf0, 4, 0);                                                     \
    if ((VMODE) == 1) asm volatile("s_waitcnt vmcnt(4)" ::: "memory");          \
    if ((VMODE) == 2) asm volatile("s_waitcnt vmcnt(0)" ::: "memory");          \
    __builtin_amdgcn_s_barrier();                                               \
  } while (0)

template <int MODE>
__global__ __launch_bounds__(512, 2) void gemm_bt(const unsigned short* __restrict__ A,
                                                  const unsigned short* __restrict__ B,
                                                  const float* __restrict__ bias,
                                                  void* __restrict__ Cout,
                                                  int M, int Nn, int K) {
  __shared__ __align__(16) char smem[131072];

  const int tid   = threadIdx.x;
  const int wid   = tid >> 6;
  const int lane  = tid & 63;
  const int col16 = lane & 15;
  const int quad  = lane >> 4;
  const int wr = wid >> 2;       // 0..1 : M half (rows wr*128..+127)
  const int wc = wid & 3;        // 0..3 : N quarter (cols wc*64..+63)
  const long arow0 = (long)blockIdx.x * 256;
  const long bcol0 = (long)blockIdx.y * 256;

  // ---- read-address constants (swizzled) ----
  const int axor = (col16 & 7) << 4;
  int akt[2];
  akt[0] = (quad * 16) ^ axor;
  akt[1] = (64 + quad * 16) ^ axor;
  const int aRB = col16 * 128;                    // within-slot A row base
  const int bRB = ((wc & 1) * 64 + col16) * 128;  // within-slot B row base

  // ---- staging constants (inverse-swizzled global source) ----
  const int srowt = tid >> 3;                                   // 0..63
  const int skoff = (((tid & 7) * 16) ^ ((srowt & 7) << 4)) >> 1;  // shorts

  const int NT = K >> 6;   // K-tiles of 64 (even, >= 4)

  // prologue: tile0 all 4 halves + B-lo(1) + A-lo(1)  (6 stage-ops, 12 loads)
  STAGE_H(0, 0, 0, 0);      // A-lo(0) -> A-slot0
  STAGE_H(0, 1, 1, 0);      // A-hi(0) -> A-slot1
  STAGE_H(1, 0, 0, 0);      // B-lo(0) -> B-slot0
  STAGE_H(1, 1, 1, 0);      // B-hi(0) -> B-slot1
  STAGE_H(1, 0, 2, 64);     // B-lo(1) -> B-slot2
  STAGE_H(0, 0, 2, 64);     // A-lo(1) -> A-slot2

  const f32x4 fzero = {0.f, 0.f, 0.f, 0.f};
  f32x4 acc[8][4];
#pragma unroll
  for (int i = 0; i < 8; i++)
#pragma unroll
    for (int j = 0; j < 4; j++) acc[i][j] = fzero;

  asm volatile("s_waitcnt vmcnt(4)" ::: "memory");  // tile 0 resident
  __builtin_amdgcn_s_barrier();

  // main loop: full-stage tiles 0..NT-3 in pairs
#pragma unroll 1
  for (int u = 0; u + 4 <= NT; u += 2) {
    TILE_T(0, (u + 1) * 64, (u + 2) * 64, 1, 1, 1);
    TILE_T(2, (u + 2) * 64, (u + 3) * 64, 1, 1, 1);
  }
  // tail: tile NT-2 stages only hi-halves of NT-1; tile NT-1 stages nothing
  TILE_T(0, (NT - 1) * 64, 0, 1, 0, 2);
  TILE_T(2, 0, 0, 0, 0, 0);

  // ---- epilogue: 8 slabs of 32 rows x 256 cols through LDS ----
  // C/D frag: row = quad*4 + rr, col = col16 (verified layout).
  float bcol[4];
#pragma unroll
  for (int nf = 0; nf < 4; nf++) bcol[nf] = bias[bcol0 + wc * 64 + nf * 16 + col16];

  const int erow = tid >> 4;   // 0..31
  const int ecc  = tid & 15;   // 16-col chunk

  if (MODE != 2) {
    unsigned short* epi = (unsigned short*)smem;
    const int EST = 264;  // shorts; 528 B row stride (16B-aligned, bank-skewed)
#pragma unroll
    for (int s = 0; s < 8; s++) {
      if ((s >> 2) == wr) {
        const int mfb = (s & 3) * 2;
#pragma unroll
        for (int ml = 0; ml < 2; ml++)
#pragma unroll
          for (int nf = 0; nf < 4; nf++)
#pragma unroll
            for (int rr = 0; rr < 4; rr++) {
              float vv = acc[mfb + ml][nf][rr] + bcol[nf];
              if (MODE == 0) vv = (vv > 0.f) ? (vv + 1.f) : __expf(vv);  // elu+1
              epi[(ml * 16 + quad * 4 + rr) * EST + wc * 64 + nf * 16 + col16] =
                  f2bf(vv);
            }
      }
      __syncthreads();
      {
        const long gr = arow0 + s * 32 + erow;
        const unsigned short* srcp = &epi[erow * EST + ecc * 16];
        uint4 a  = *(const uint4*)srcp;
        uint4 b2 = *(const uint4*)(srcp + 8);
        unsigned short* Cp = (unsigned short*)Cout + gr * Nn + bcol0 + ecc * 16;
        *(uint4*)Cp       = a;
        *(uint4*)(Cp + 8) = b2;
      }
      __syncthreads();
    }
  } else {
    float* epi = (float*)smem;
    const int ESF = 260;  // floats; 1040 B row stride (16B-aligned, bank-skewed)
#pragma unroll
    for (int s = 0; s < 8; s++) {
      if ((s >> 2) == wr) {
        const int mfb = (s & 3) * 2;
#pragma unroll
        for (int ml = 0; ml < 2; ml++)
#pragma unroll
          for (int nf = 0; nf < 4; nf++)
#pragma unroll
            for (int rr = 0; rr < 4; rr++)
              epi[(ml * 16 + quad * 4 + rr) * ESF + wc * 64 + nf * 16 + col16] =
                  acc[mfb + ml][nf][rr] + bcol[nf];
      }
      __syncthreads();
      {
        const long gr = arow0 + s * 32 + erow;
        const float* srcp = &epi[erow * ESF + ecc * 16];
        float* Cp = (float*)Cout + gr * Nn + bcol0 + ecc * 16;
#pragma unroll
        for (int s4 = 0; s4 < 4; s4++)
          *(float4*)(Cp + s4 * 4) = *(const float4*)(srcp + s4 * 4);
      }
      __syncthreads();
    }
  }
}

// ---------------- kv partials: kv[d][e] = sum_l kf[l][d]*v[l][e] ------------
// grid (NHG, NCHUNK), block 256. Non-atomic partial outputs per chunk.
__global__ __launch_bounds__(256) void kv_partial_kernel(const unsigned short* __restrict__ kf,
                                                         const unsigned short* __restrict__ vp,
                                                         float* __restrict__ kvp,
                                                         float* __restrict__ ksp) {
  __shared__ float ks[32 * 64];
  __shared__ float vs[32 * 64];
  const int hg = blockIdx.x;
  const int chunk = blockIdx.y;
  const int n = hg >> 4, h = hg & 15;
  const int tid = threadIdx.x;
  const int td = tid >> 4, te = tid & 15;   // thread covers d=td*4..+3, e=te*4..+3
  const long hoff = (long)n * EMB + h * HDIM;
  const int l0 = chunk * LCHUNK;

  float acc[4][4];
#pragma unroll
  for (int i = 0; i < 4; i++)
#pragma unroll
    for (int j = 0; j < 4; j++) acc[i][j] = 0.f;
  float ksacc[4] = {0.f, 0.f, 0.f, 0.f};

  const int lrow = tid >> 3;         // 0..31
  const int dcol = (tid & 7) * 8;    // 0..56

  for (int ls = 0; ls < LCHUNK; ls += 32) {
    const long g = (long)(l0 + ls + lrow) * (NBATCH * EMB) + hoff + dcol;
    uint4 kr = *(const uint4*)(kf + g);
    uint4 vr = *(const uint4*)(vp + g);
    float* kd = &ks[lrow * 64 + dcol];
    float* vd = &vs[lrow * 64 + dcol];
    uint32_t ku[4] = {kr.x, kr.y, kr.z, kr.w};
    uint32_t vu[4] = {vr.x, vr.y, vr.z, vr.w};
#pragma unroll
    for (int t2 = 0; t2 < 4; t2++) {
      kd[2 * t2]     = bf2f((unsigned short)(ku[t2] & 0xffffu));
      kd[2 * t2 + 1] = bf2f((unsigned short)(ku[t2] >> 16));
      vd[2 * t2]     = bf2f((unsigned short)(vu[t2] & 0xffffu));
      vd[2 * t2 + 1] = bf2f((unsigned short)(vu[t2] >> 16));
    }
    __syncthreads();
#pragma unroll
    for (int l = 0; l < 32; l++) {
      float kq[4], vq[4];
      *(float4*)kq = *(const float4*)(&ks[l * 64 + td * 4]);
      *(float4*)vq = *(const float4*)(&vs[l * 64 + te * 4]);
#pragma unroll
      for (int i = 0; i < 4; i++) {
        ksacc[i] += kq[i];
#pragma unroll
        for (int j = 0; j < 4; j++) acc[i][j] += kq[i] * vq[j];
      }
    }
    __syncthreads();
  }
  float* outp = kvp + ((long)chunk * NHG + hg) * 4096;
#pragma unroll
  for (int i = 0; i < 4; i++)
#pragma unroll
    for (int j = 0; j < 4; j++)
      outp[(td * 4 + i) * 64 + te * 4 + j] = acc[i][j];
  if (te == 0) {
    float* o2 = ksp + ((long)chunk * NHG + hg) * 64;
#pragma unroll
    for (int i = 0; i < 4; i++) o2[td * 4 + i] = ksacc[i];
  }
}

// ---------------- out1 = (qf @ kv) * 1/(qf.ksum + eps), bf16 row-major ------
// grid (NHG, 16), block 256 (4 waves). MFMA version; kvp reduce
// float4-vectorized (32 dwordx4 vs 128 scalar dword loads per thread).
__global__ __launch_bounds__(256) void attn_out_kernel(const unsigned short* __restrict__ qf,
                                                       const float* __restrict__ kvp,
                                                       const float* __restrict__ ksp,
                                                       unsigned short* __restrict__ out1) {
  __shared__ __align__(16) char smem[53248];
  const int hg = blockIdx.x;
  const int lc = blockIdx.y;
  const int n = hg >> 4, h = hg & 15;
  const int tid = threadIdx.x;
  const int wid = tid >> 6;
  const int lane = tid & 63;
  const int col16 = lane & 15;
  const int quad  = lane >> 4;
  const long lbase = (long)lc * 256;

  // ---- stage A = qf[lbase..+255][h*64..+63] via gload_lds (swizzled source)
#pragma unroll
  for (int r = 0; r < 8; r++) {
    const int row = r * 32 + (tid >> 3);
    const long l = lbase + row;
    const int sk = (((tid & 7) * 16) ^ ((row & 7) << 4)) >> 1;   // shorts
    const unsigned short* gp = qf + (l * NBATCH + n) * (long)EMB + h * HDIM + sk;
    __builtin_amdgcn_global_load_lds(
        (const __attribute__((address_space(1))) void*)gp,
        (__attribute__((address_space(3))) void*)(smem + r * 4096 + tid * 16),
        16, 0, 0);
  }

  // ---- build B: reduce kv partials (float4 loads), hi/lo split, transposed
  //      swizzled writes
  char* Bl = smem + 32768;
  for (int wb = tid * 4; wb < 4096; wb += 1024) {
    float4 s = make_float4(0.f, 0.f, 0.f, 0.f);
#pragma unroll
    for (int c = 0; c < NCHUNK; c++) {
      const float4 t = *(const float4*)(kvp + ((long)c * NHG + hg) * 4096 + wb);
      s.x += t.x; s.y += t.y; s.z += t.z; s.w += t.w;
    }
    const int d = wb >> 6;      // wb%64 in {0,4,..,60}: all 4 elems same d
    const int e0 = wb & 63;
    float sv[4] = {s.x, s.y, s.z, s.w};
#pragma unroll
    for (int j = 0; j < 4; j++) {
      const int e = e0 + j;
      const unsigned short hi = f2bf(sv[j]);
      const unsigned short lo = f2bf(sv[j] - bf2f(hi));
      const int key = (e & 7) << 4;
      *(unsigned short*)(Bl + e * 256 + ((2 * d) ^ key))       = hi;
      *(unsigned short*)(Bl + e * 256 + ((128 + 2 * d) ^ key)) = lo;
    }
  }
  if (tid < 64) {
    float s = 0.f;
#pragma unroll
    for (int c = 0; c < NCHUNK; c++) s += ksp[((long)c * NHG + hg) * 64 + tid];
    const unsigned short hi = f2bf(s);
    const unsigned short lo = f2bf(s - bf2f(hi));
    *(unsigned short*)(Bl + 64 * 256 + 2 * tid)       = hi;   // row 64: key=0
    *(unsigned short*)(Bl + 64 * 256 + 128 + 2 * tid) = lo;
  }
  {  // zero rows 65..79
    uint32_t* zb = (uint32_t*)(Bl + 65 * 256);
    for (int i = tid; i < 15 * 64; i += 256) zb[i] = 0u;
  }
  __syncthreads();

  // ---- MFMA: per wave 64 l-rows x 80 cols, logical K=128 (hi pass + lo pass)
  const int wl0 = wid * 64;
  const int akey = (col16 & 7) << 4;

  bf16x8 af[4][2];
#pragma unroll
  for (int mi = 0; mi < 4; mi++)
#pragma unroll
    for (int ks = 0; ks < 2; ks++)
      af[mi][ks] = *(const bf16x8*)(smem + (wl0 + mi * 16 + col16) * 128 +
                                    ((ks * 64 + quad * 16) ^ akey));

  const f32x4 fzero = {0.f, 0.f, 0.f, 0.f};
  f32x4 acc[4][5];
#pragma unroll
  for (int mi = 0; mi < 4; mi++)
#pragma unroll
    for (int nf = 0; nf < 5; nf++) acc[mi][nf] = fzero;

#pragma unroll
  for (int nf = 0; nf < 5; nf++) {
    bf16x8 bfr[4];
#pragma unroll
    for (int pass = 0; pass < 2; pass++)
#pragma unroll
      for (int ks = 0; ks < 2; ks++)
        bfr[pass * 2 + ks] = *(const bf16x8*)(Bl + (nf * 16 + col16) * 256 +
                                              ((pass * 128 + ks * 64 + quad * 16) ^ akey));
#pragma unroll
    for (int mi = 0; mi < 4; mi++)
#pragma unroll
      for (int pass = 0; pass < 2; pass++)
#pragma unroll
        for (int ks = 0; ks < 2; ks++)
          acc[mi][nf] = __builtin_amdgcn_mfma_f32_16x16x32_bf16(
              af[mi][ks], bfr[pass * 2 + ks], acc[mi][nf], 0, 0, 0);
  }

  __syncthreads();   // all A reads done; reuse A region as epilogue buffer

  // ---- epilogue: z from denom col (lane quad*16 holds col 64), swizzled LDS
  unsigned short* epi = (unsigned short*)smem;
#pragma unroll
  for (int mi = 0; mi < 4; mi++) {
#pragma unroll
    for (int rr = 0; rr < 4; rr++) {
      const float dv = __shfl(acc[mi][4][rr], lane & 48);
      const float z = 1.f / (dv + 1e-6f);
      const int row = wl0 + mi * 16 + quad * 4 + rr;
      const int key = (row & 7) << 4;
#pragma unroll
      for (int nf = 0; nf < 4; nf++)
        *(unsigned short*)((char*)epi + row * 128 +
                           (((nf * 16 + col16) * 2) ^ key)) =
            f2bf(acc[mi][nf][rr] * z);
    }
  }
  __syncthreads();

  // packed readback: thread -> one row chunk of 16 B per pass, 8 passes
#pragma unroll
  for (int r = 0; r < 8; r++) {
    const int row = r * 32 + (tid >> 3);
    const long l = lbase + row;
    const uint4 vv = *(const uint4*)((char*)epi + row * 128 +
                                     (((tid & 7) * 16) ^ ((row & 7) << 4)));
    *(uint4*)(out1 + (l * NBATCH + n) * (long)EMB + h * HDIM + (tid & 7) * 8) = vv;
  }
}

// ---------------------------------------------------------------------------
extern "C" void kernel_launch(void* const* d_in, const int* in_sizes, int n_in,
                              void* d_out, int out_size, void* d_ws, size_t ws_size,
                              hipStream_t stream) {
  const float* q  = (const float*)d_in[0];
  const float* k  = (const float*)d_in[1];
  const float* v  = (const float*)d_in[2];
  const float* Wq = (const float*)d_in[3];
  const float* bq = (const float*)d_in[4];
  const float* Wk = (const float*)d_in[5];
  const float* bk = (const float*)d_in[6];
  const float* Wv = (const float*)d_in[7];
  const float* bv = (const float*)d_in[8];
  const float* Wo = (const float*)d_in[9];
  const float* bo = (const float*)d_in[10];

  char* ws = (char*)d_ws;
  const size_t BUF = (size_t)MROWS * EMB * 2;  // 33,554,432 B
  unsigned short* T0  = (unsigned short*)(ws);              // A-staging / out1
  unsigned short* qf  = (unsigned short*)(ws + BUF);
  unsigned short* kf  = (unsigned short*)(ws + 2 * BUF);
  unsigned short* vp  = (unsigned short*)(ws + 3 * BUF);
  unsigned short* Wqb = (unsigned short*)(ws + 4 * BUF);
  unsigned short* Wkb = Wqb + (size_t)EMB * EMB;
  unsigned short* Wvb = Wkb + (size_t)EMB * EMB;
  unsigned short* Wob = Wvb + (size_t)EMB * EMB;
  float* kvp = (float*)(ws + 4 * BUF + 4 * (size_t)EMB * EMB * 2);
  float* ksp = kvp + (size_t)NCHUNK * NHG * HDIM * HDIM;

  const int nQKV = MROWS * EMB;     // 16,777,216
  const int nW   = EMB * EMB;       // 1,048,576

  // all 4 weight matrices -> bf16 in one dispatch
  convert_w4<<<dim3(nW / 1024, 4), 256, 0, stream>>>(Wq, Wk, Wv, Wo,
                                                     Wqb, Wkb, Wvb, Wob, nW);

  dim3 gg(MROWS / 256, EMB / 256), bb(512);

  // projections (T0 reused as bf16 A-staging between GEMMs; stream-ordered,
  // interleaved convert->gemm keeps each A-buffer L3-hot at its consumer)
  convert_kernel<<<nQKV / 1024, 256, 0, stream>>>(q, T0, nQKV);
  gemm_bt<0><<<gg, bb, 0, stream>>>(T0, Wqb, bq, qf, MROWS, EMB, EMB);
  convert_kernel<<<nQKV / 1024, 256, 0, stream>>>(k, T0, nQKV);
  gemm_bt<0><<<gg, bb, 0, stream>>>(T0, Wkb, bk, kf, MROWS, EMB, EMB);
  convert_kernel<<<nQKV / 1024, 256, 0, stream>>>(v, T0, nQKV);
  gemm_bt<1><<<gg, bb, 0, stream>>>(T0, Wvb, bv, vp, MROWS, EMB, EMB);

  // attention state + output (out1 -> T0)
  kv_partial_kernel<<<dim3(NHG, NCHUNK), 256, 0, stream>>>(kf, vp, kvp, ksp);
  attn_out_kernel<<<dim3(NHG, L_SEQ / 256), 256, 0, stream>>>(qf, kvp, ksp, T0);

  // final projection -> fp32 output
  gemm_bt<2><<<gg, bb, 0, stream>>>(T0, Wob, bo, d_out, MROWS, EMB, EMB);
}

// Round 11
// 437.469 us; speedup vs baseline: 1.0604x; 1.0355x over previous
//
#include <hip/hip_runtime.h>
#include <hip/hip_bf16.h>
#include <cstdint>

// ---------------------------------------------------------------------------
// LinearAttention on MI355X (gfx950)
// L=4096, N=4, E=1024, H=16, D=64.  M = L*N = 16384.
// Round 15: MFMA-ize kv_partial (was pure VALU outer-product, ~30-35 us,
// MfmaUtil=0 -- the last Guideline-10 violation). kv[d][e] = sum_l kf.v with
// K=l: both operands reg-staged + transpose-written to LDS (ks_t[64][72],
// vs_t[80][72] bf16; stride 72 shorts = 16B-aligned b128 rows, <=2-way read
// conflicts). Fragment conventions identical to the verified gemm (col16 =
// non-K input index; C row=quad*4+rr, col=col16). ksum folded as ones-column
// (vs_t row 64 = 1.0 -> C col 64 = ksum, same trick as attn_out's denom).
// Output layout unchanged -> attn_out untouched.
// Everything else identical to R7/R10 (reproduced best: 453.0 us).
// ---------------------------------------------------------------------------

typedef __attribute__((ext_vector_type(8))) short bf16x8;
typedef __attribute__((ext_vector_type(4))) float f32x4;

#define L_SEQ 4096
#define NBATCH 4
#define EMB 1024
#define NHEADS 16
#define HDIM 64
#define MROWS (L_SEQ * NBATCH)   // 16384
#define NHG (NBATCH * NHEADS)    // 64 head-groups
#define LCHUNK 512
#define NCHUNK (L_SEQ / LCHUNK)  // 8
#define KTS 72                   // kv_partial LDS l-stride (shorts)

__device__ __forceinline__ unsigned short f2bf(float f) {
  union { float f; uint32_t u; } v; v.f = f;
  uint32_t u = v.u;
  u += 0x7fffu + ((u >> 16) & 1u);   // round-to-nearest-even
  return (unsigned short)(u >> 16);
}
__device__ __forceinline__ float bf2f(unsigned short s) {
  union { uint32_t u; float f; } v; v.u = ((uint32_t)s) << 16;
  return v.f;
}
__device__ __forceinline__ uint32_t pkbf(float a, float b) {
  union { float f; uint32_t u; } ua, ub; ua.f = a; ub.f = b;
  return ((ua.u + 0x8000u) >> 16) | ((ub.u + 0x8000u) & 0xffff0000u);
}

// ---------------- fp32 -> bf16 convert ---------------------------------------
__global__ __launch_bounds__(256) void convert_kernel(const float* __restrict__ src,
                                                      unsigned short* __restrict__ dst,
                                                      int n) {
  int i = (blockIdx.x * 256 + threadIdx.x) * 4;
  if (i + 4 <= n) {
    float4 f = *(const float4*)(src + i);
    uint2 p;
    p.x = pkbf(f.x, f.y);
    p.y = pkbf(f.z, f.w);
    *(uint2*)(dst + i) = p;
  }
}

// ---------------- fp32 -> bf16 convert, 4 weight matrices -------------------
__global__ __launch_bounds__(256) void convert_w4(const float* __restrict__ s0,
                                                  const float* __restrict__ s1,
                                                  const float* __restrict__ s2,
                                                  const float* __restrict__ s3,
                                                  unsigned short* __restrict__ d0,
                                                  unsigned short* __restrict__ d1,
                                                  unsigned short* __restrict__ d2,
                                                  unsigned short* __restrict__ d3,
                                                  int n) {
  const int w = blockIdx.y;
  const float* src = (w == 0) ? s0 : (w == 1) ? s1 : (w == 2) ? s2 : s3;
  unsigned short* dst = (w == 0) ? d0 : (w == 1) ? d1 : (w == 2) ? d2 : d3;
  int i = (blockIdx.x * 256 + threadIdx.x) * 4;
  if (i + 4 <= n) {
    float4 f = *(const float4*)(src + i);
    uint2 p;
    p.x = pkbf(f.x, f.y);
    p.y = pkbf(f.z, f.w);
    *(uint2*)(dst + i) = p;
  }
}

// ---------------- bf16 MFMA GEMM: C = A(MxK) . B(NnxK)^T + bias -------------
// MODE 0: elu(x)+1 -> bf16 ; MODE 1: x -> bf16 ; MODE 2: x -> fp32
// M % 256 == 0, Nn % 256 == 0, K % 128 == 0 (NT = K/64 even, >= 4).
// 512 threads (8 waves: wr = wid>>2 in {0,1} -> M; wc = wid&3 -> N).
// LDS: A half-slots s*16384 (s=0..3), B half-slots 65536 + s*16384 (128 KB).
// Half-tile (128 rows x 64 k) of tile u, half h lives in slot (2u+h)&3.
// Swizzle: within a 128 B row, byte ^= ((row&7)<<4) (involution; applied to
// the gload_lds GLOBAL source and to ds_read addresses; LDS dest stays linear).

// stage one 128x64 half-tile: MATB 0=A/1=B, RH row-half, SLOT, KTN k-offset.
#define STAGE_H(MATB, RH, SLOT, KTN)                                            \
  do {                                                                          \
    _Pragma("unroll")                                                           \
    for (int r_ = 0; r_ < 2; r_++) {                                            \
      const long grow_ = ((MATB) ? bcol0 : arow0) + (RH) * 128 + r_ * 64 + srowt;\
      const unsigned short* gp_ =                                               \
          ((MATB) ? B : A) + grow_ * (long)K + (KTN) + skoff;                   \
      __builtin_amdgcn_global_load_lds(                                         \
          (const __attribute__((address_space(1))) void*)gp_,                   \
          (__attribute__((address_space(3))) void*)(smem + (MATB) * 65536 +     \
              (SLOT) * 16384 + r_ * 8192 + wid * 1024),                         \
          16, 0, 0);                                                            \
    }                                                                           \
  } while (0)

// one 16-MFMA cluster: C quadrant rows MFB..MFB+3 x cols NFB..NFB+1, K=64
#define MFMA_Q(AF, BF, MFB, NFB)                                                \
  do {                                                                          \
    __builtin_amdgcn_s_setprio(1);                                              \
    _Pragma("unroll")                                                           \
    for (int mi_ = 0; mi_ < 4; mi_++)                                           \
      _Pragma("unroll")                                                         \
      for (int ni_ = 0; ni_ < 2; ni_++)                                         \
        _Pragma("unroll")                                                       \
        for (int ks_ = 0; ks_ < 2; ks_++)                                       \
          acc[(MFB) + mi_][(NFB) + ni_] =                                       \
              __builtin_amdgcn_mfma_f32_16x16x32_bf16(                          \
                  AF[mi_ * 2 + ks_], BF[ni_ * 2 + ks_],                         \
                  acc[(MFB) + mi_][(NFB) + ni_], 0, 0, 0);                      \
    __builtin_amdgcn_s_setprio(0);                                              \
  } while (0)

#define PH_SYNC                                                                 \
  __builtin_amdgcn_s_barrier();                                                 \
  asm volatile("s_waitcnt lgkmcnt(0)" ::: "memory");                            \
  __builtin_amdgcn_sched_barrier(0);

// one K-tile u (A/B lo slots at SA, hi at SA+1; SA in {0,2} = (2u)&3).
// Stages: ph0 A-hi(u+1)->slot SA^3 (iff S01), ph1 B-hi(u+1)->SA^3 (iff S01),
//         ph2 B-lo(u+2)->SA (iff S23),        ph3 A-lo(u+2)->SA (iff S23).
// VMODE: 1 = boundary vmcnt(4) (steady), 2 = vmcnt(0) (tail fill), 0 = none.
#define TILE_T(SA, K1, K2, S01, S23, VMODE)                                     \
  do {                                                                          \
    bf16x8 af0[8], af1[8], bf0[4], bf1[4];                                      \
    /* ph0: read A rows 0-63 of half wr + B rows lo; stage A-hi(u+1) */         \
    _Pragma("unroll")                                                           \
    for (int mi_ = 0; mi_ < 4; mi_++)                                           \
      _Pragma("unroll")                                                         \
      for (int ks_ = 0; ks_ < 2; ks_++)                                         \
        af0[mi_ * 2 + ks_] = *(const bf16x8*)(smem + ((SA) + wr) * 16384 + aRB +\
                                              mi_ * 2048 + akt[ks_]);           \
    _Pragma("unroll")                                                           \
    for (int ni_ = 0; ni_ < 2; ni_++)                                           \
      _Pragma("unroll")                                                         \
      for (int ks_ = 0; ks_ < 2; ks_++)                                         \
        bf0[ni_ * 2 + ks_] = *(const bf16x8*)(smem + 65536 +                    \
                                              ((SA) + (wc >> 1)) * 16384 + bRB +\
                                              ni_ * 2048 + akt[ks_]);           \
    if (S01) STAGE_H(0, 1, (SA) ^ 3, K1);                                       \
    PH_SYNC                                                                     \
    MFMA_Q(af0, bf0, 0, 0);                                                     \
    __builtin_amdgcn_s_barrier();                                               \
    /* ph1: read B rows hi; stage B-hi(u+1) */                                  \
    _Pragma("unroll")                                                           \
    for (int ni_ = 0; ni_ < 2; ni_++)                                           \
      _Pragma("unroll")                                                         \
      for (int ks_ = 0; ks_ < 2; ks_++)                                         \
        bf1[ni_ * 2 + ks_] = *(const bf16x8*)(smem + 65536 +                    \
                                              ((SA) + (wc >> 1)) * 16384 + bRB +\
                                              (ni_ + 2) * 2048 + akt[ks_]);     \
    if (S01) STAGE_H(1, 1, (SA) ^ 3, K1);                                       \
    PH_SYNC                                                                     \
    MFMA_Q(af0, bf1, 0, 2);                                                     \
    __builtin_amdgcn_s_barrier();                                               \
    /* ph2: read A rows 64-127; stage B-lo(u+2) */                              \
    _Pragma("unroll")                                                           \
    for (int mi_ = 0; mi_ < 4; mi_++)                                           \
      _Pragma("unroll")                                                         \
      for (int ks_ = 0; ks_ < 2; ks_++)                                         \
        af1[mi_ * 2 + ks_] = *(const bf16x8*)(smem + ((SA) + wr) * 16384 + aRB +\
                                              (mi_ + 4) * 2048 + akt[ks_]);     \
    if (S23) STAGE_H(1, 0, (SA), K2);                                           \
    PH_SYNC                                                                     \
    MFMA_Q(af1, bf1, 4, 2);                                                     \
    __builtin_amdgcn_s_barrier();                                               \
    /* ph3: no reads; stage A-lo(u+2); counted boundary wait */                 \
    if (S23) STAGE_H(0, 0, (SA), K2);                                           \
    PH_SYNC                                                                     \
    MFMA_Q(af1, bf0, 4, 0);                                                     \
    if ((VMODE) == 1) asm volatile("s_waitcnt vmcnt(4)" ::: "memory");          \
    if ((VMODE) == 2) asm volatile("s_waitcnt vmcnt(0)" ::: "memory");          \
    __builtin_amdgcn_s_barrier();                                               \
  } while (0)

template <int MODE>
__global__ __launch_bounds__(512, 2) void gemm_bt(const unsigned short* __restrict__ A,
                                                  const unsigned short* __restrict__ B,
                                                  const float* __restrict__ bias,
                                                  void* __restrict__ Cout,
                                                  int M, int Nn, int K) {
  __shared__ __align__(16) char smem[131072];

  const int tid   = threadIdx.x;
  const int wid   = tid >> 6;
  const int lane  = tid & 63;
  const int col16 = lane & 15;
  const int quad  = lane >> 4;
  const int wr = wid >> 2;       // 0..1 : M half (rows wr*128..+127)
  const int wc = wid & 3;        // 0..3 : N quarter (cols wc*64..+63)
  const long arow0 = (long)blockIdx.x * 256;
  const long bcol0 = (long)blockIdx.y * 256;

  // ---- read-address constants (swizzled) ----
  const int axor = (col16 & 7) << 4;
  int akt[2];
  akt[0] = (quad * 16) ^ axor;
  akt[1] = (64 + quad * 16) ^ axor;
  const int aRB = col16 * 128;                    // within-slot A row base
  const int bRB = ((wc & 1) * 64 + col16) * 128;  // within-slot B row base

  // ---- staging constants (inverse-swizzled global source) ----
  const int srowt = tid >> 3;                                   // 0..63
  const int skoff = (((tid & 7) * 16) ^ ((srowt & 7) << 4)) >> 1;  // shorts

  const int NT = K >> 6;   // K-tiles of 64 (even, >= 4)

  // prologue: tile0 all 4 halves + B-lo(1) + A-lo(1)  (6 stage-ops, 12 loads)
  STAGE_H(0, 0, 0, 0);      // A-lo(0) -> A-slot0
  STAGE_H(0, 1, 1, 0);      // A-hi(0) -> A-slot1
  STAGE_H(1, 0, 0, 0);      // B-lo(0) -> B-slot0
  STAGE_H(1, 1, 1, 0);      // B-hi(0) -> B-slot1
  STAGE_H(1, 0, 2, 64);     // B-lo(1) -> B-slot2
  STAGE_H(0, 0, 2, 64);     // A-lo(1) -> A-slot2

  const f32x4 fzero = {0.f, 0.f, 0.f, 0.f};
  f32x4 acc[8][4];
#pragma unroll
  for (int i = 0; i < 8; i++)
#pragma unroll
    for (int j = 0; j < 4; j++) acc[i][j] = fzero;

  asm volatile("s_waitcnt vmcnt(4)" ::: "memory");  // tile 0 resident
  __builtin_amdgcn_s_barrier();

  // main loop: full-stage tiles 0..NT-3 in pairs
#pragma unroll 1
  for (int u = 0; u + 4 <= NT; u += 2) {
    TILE_T(0, (u + 1) * 64, (u + 2) * 64, 1, 1, 1);
    TILE_T(2, (u + 2) * 64, (u + 3) * 64, 1, 1, 1);
  }
  // tail: tile NT-2 stages only hi-halves of NT-1; tile NT-1 stages nothing
  TILE_T(0, (NT - 1) * 64, 0, 1, 0, 2);
  TILE_T(2, 0, 0, 0, 0, 0);

  // ---- epilogue: 8 slabs of 32 rows x 256 cols through LDS ----
  // C/D frag: row = quad*4 + rr, col = col16 (verified layout).
  float bcol[4];
#pragma unroll
  for (int nf = 0; nf < 4; nf++) bcol[nf] = bias[bcol0 + wc * 64 + nf * 16 + col16];

  const int erow = tid >> 4;   // 0..31
  const int ecc  = tid & 15;   // 16-col chunk

  if (MODE != 2) {
    unsigned short* epi = (unsigned short*)smem;
    const int EST = 264;  // shorts; 528 B row stride (16B-aligned, bank-skewed)
#pragma unroll
    for (int s = 0; s < 8; s++) {
      if ((s >> 2) == wr) {
        const int mfb = (s & 3) * 2;
#pragma unroll
        for (int ml = 0; ml < 2; ml++)
#pragma unroll
          for (int nf = 0; nf < 4; nf++)
#pragma unroll
            for (int rr = 0; rr < 4; rr++) {
              float vv = acc[mfb + ml][nf][rr] + bcol[nf];
              if (MODE == 0) vv = (vv > 0.f) ? (vv + 1.f) : __expf(vv);  // elu+1
              epi[(ml * 16 + quad * 4 + rr) * EST + wc * 64 + nf * 16 + col16] =
                  f2bf(vv);
            }
      }
      __syncthreads();
      {
        const long gr = arow0 + s * 32 + erow;
        const unsigned short* srcp = &epi[erow * EST + ecc * 16];
        uint4 a  = *(const uint4*)srcp;
        uint4 b2 = *(const uint4*)(srcp + 8);
        unsigned short* Cp = (unsigned short*)Cout + gr * Nn + bcol0 + ecc * 16;
        *(uint4*)Cp       = a;
        *(uint4*)(Cp + 8) = b2;
      }
      __syncthreads();
    }
  } else {
    float* epi = (float*)smem;
    const int ESF = 260;  // floats; 1040 B row stride (16B-aligned, bank-skewed)
#pragma unroll
    for (int s = 0; s < 8; s++) {
      if ((s >> 2) == wr) {
        const int mfb = (s & 3) * 2;
#pragma unroll
        for (int ml = 0; ml < 2; ml++)
#pragma unroll
          for (int nf = 0; nf < 4; nf++)
#pragma unroll
            for (int rr = 0; rr < 4; rr++)
              epi[(ml * 16 + quad * 4 + rr) * ESF + wc * 64 + nf * 16 + col16] =
                  acc[mfb + ml][nf][rr] + bcol[nf];
      }
      __syncthreads();
      {
        const long gr = arow0 + s * 32 + erow;
        const float* srcp = &epi[erow * ESF + ecc * 16];
        float* Cp = (float*)Cout + gr * Nn + bcol0 + ecc * 16;
#pragma unroll
        for (int s4 = 0; s4 < 4; s4++)
          *(float4*)(Cp + s4 * 4) = *(const float4*)(srcp + s4 * 4);
      }
      __syncthreads();
    }
  }
}

// ---------------- kv partials via MFMA --------------------------------------
// kv[d][e] = sum_l kf[l][d]*v[l][e]; ksum[d] = sum_l kf[l][d].
// grid (NHG, NCHUNK), block 256 (4 waves). Wave w computes d-band w*16..+15
// x 80 cols: e 0..63 = kv, col 64 = ksum (ones-column), 65..79 discarded.
// LDS: ks_t [64 d][KTS l] bf16, vs_t [80 e][KTS l] bf16 (transposed staging;
// KTS=72 shorts keeps b128 rows 16B-aligned; read conflicts <=2-way).
// Fragment conventions = gemm_bt (col16 = non-K input index, quad*8 = k;
// C row = quad*4+rr, col = col16 -- verified layout).
__global__ __launch_bounds__(256) void kv_partial_kernel(const unsigned short* __restrict__ kf,
                                                         const unsigned short* __restrict__ vp,
                                                         float* __restrict__ kvp,
                                                         float* __restrict__ ksp) {
  __shared__ __align__(16) unsigned short ks_t[64 * KTS];
  __shared__ __align__(16) unsigned short vs_t[80 * KTS];
  const int hg = blockIdx.x;
  const int chunk = blockIdx.y;
  const int n = hg >> 4, h = hg & 15;
  const int tid = threadIdx.x;
  const int wid = tid >> 6;
  const int lane = tid & 63;
  const int col16 = lane & 15;
  const int quad  = lane >> 4;
  const long hoff = (long)n * EMB + h * HDIM;
  const int l0 = chunk * LCHUNK;

  // staging assignment: thread covers l = tid>>2 (0..63), d0 = (tid&3)*16
  const int sl  = tid >> 2;
  const int sd0 = (tid & 3) * 16;

  // init B rows 64..79: row 64 = 1.0 (ksum column), rows 65..79 = 0
  for (int i = tid; i < 16 * KTS; i += 256)
    vs_t[64 * KTS + i] = (i < KTS) ? (unsigned short)0x3F80u : (unsigned short)0u;

  const f32x4 fzero = {0.f, 0.f, 0.f, 0.f};
  f32x4 acc[5];
#pragma unroll
  for (int nf = 0; nf < 5; nf++) acc[nf] = fzero;

  for (int ls = 0; ls < LCHUNK; ls += 64) {
    // issue global loads (16 bf16 of kf + 16 of v for one l) before barrier
    const long g = (long)(l0 + ls + sl) * (NBATCH * EMB) + hoff + sd0;
    uint4 kr0 = *(const uint4*)(kf + g);
    uint4 kr1 = *(const uint4*)(kf + g + 8);
    uint4 vr0 = *(const uint4*)(vp + g);
    uint4 vr1 = *(const uint4*)(vp + g + 8);
    __syncthreads();   // previous slab's fragment reads complete
    {
      uint32_t ku[8] = {kr0.x, kr0.y, kr0.z, kr0.w, kr1.x, kr1.y, kr1.z, kr1.w};
      uint32_t vu[8] = {vr0.x, vr0.y, vr0.z, vr0.w, vr1.x, vr1.y, vr1.z, vr1.w};
#pragma unroll
      for (int t = 0; t < 8; t++) {
        ks_t[(sd0 + 2 * t)     * KTS + sl] = (unsigned short)(ku[t] & 0xffffu);
        ks_t[(sd0 + 2 * t + 1) * KTS + sl] = (unsigned short)(ku[t] >> 16);
        vs_t[(sd0 + 2 * t)     * KTS + sl] = (unsigned short)(vu[t] & 0xffffu);
        vs_t[(sd0 + 2 * t + 1) * KTS + sl] = (unsigned short)(vu[t] >> 16);
      }
    }
    __syncthreads();   // slab resident
#pragma unroll
    for (int kk = 0; kk < 2; kk++) {
      const bf16x8 af =
          *(const bf16x8*)(&ks_t[(wid * 16 + col16) * KTS + kk * 32 + quad * 8]);
#pragma unroll
      for (int nf = 0; nf < 5; nf++) {
        const bf16x8 bfv =
            *(const bf16x8*)(&vs_t[(nf * 16 + col16) * KTS + kk * 32 + quad * 8]);
        acc[nf] = __builtin_amdgcn_mfma_f32_16x16x32_bf16(af, bfv, acc[nf], 0, 0, 0);
      }
    }
  }

  // write partials: C row (d) = wid*16 + quad*4 + rr, col (e) = nf*16 + col16
  float* outp = kvp + ((long)chunk * NHG + hg) * 4096;
  const int dr = wid * 16 + quad * 4;
#pragma unroll
  for (int nf = 0; nf < 4; nf++)
#pragma unroll
    for (int rr = 0; rr < 4; rr++)
      outp[(dr + rr) * 64 + nf * 16 + col16] = acc[nf][rr];
  if (col16 == 0) {
    float* o2 = ksp + ((long)chunk * NHG + hg) * 64;
#pragma unroll
    for (int rr = 0; rr < 4; rr++) o2[dr + rr] = acc[4][rr];
  }
}

// ---------------- out1 = (qf @ kv) * 1/(qf.ksum + eps), bf16 row-major ------
// grid (NHG, 16), block 256 (4 waves). MFMA version; kvp reduce
// float4-vectorized (32 dwordx4 vs 128 scalar dword loads per thread).
__global__ __launch_bounds__(256) void attn_out_kernel(const unsigned short* __restrict__ qf,
                                                       const float* __restrict__ kvp,
                                                       const float* __restrict__ ksp,
                                                       unsigned short* __restrict__ out1) {
  __shared__ __align__(16) char smem[53248];
  const int hg = blockIdx.x;
  const int lc = blockIdx.y;
  const int n = hg >> 4, h = hg & 15;
  const int tid = threadIdx.x;
  const int wid = tid >> 6;
  const int lane = tid & 63;
  const int col16 = lane & 15;
  const int quad  = lane >> 4;
  const long lbase = (long)lc * 256;

  // ---- stage A = qf[lbase..+255][h*64..+63] via gload_lds (swizzled source)
#pragma unroll
  for (int r = 0; r < 8; r++) {
    const int row = r * 32 + (tid >> 3);
    const long l = lbase + row;
    const int sk = (((tid & 7) * 16) ^ ((row & 7) << 4)) >> 1;   // shorts
    const unsigned short* gp = qf + (l * NBATCH + n) * (long)EMB + h * HDIM + sk;
    __builtin_amdgcn_global_load_lds(
        (const __attribute__((address_space(1))) void*)gp,
        (__attribute__((address_space(3))) void*)(smem + r * 4096 + tid * 16),
        16, 0, 0);
  }

  // ---- build B: reduce kv partials (float4 loads), hi/lo split, transposed
  //      swizzled writes
  char* Bl = smem + 32768;
  for (int wb = tid * 4; wb < 4096; wb += 1024) {
    float4 s = make_float4(0.f, 0.f, 0.f, 0.f);
#pragma unroll
    for (int c = 0; c < NCHUNK; c++) {
      const float4 t = *(const float4*)(kvp + ((long)c * NHG + hg) * 4096 + wb);
      s.x += t.x; s.y += t.y; s.z += t.z; s.w += t.w;
    }
    const int d = wb >> 6;      // wb%64 in {0,4,..,60}: all 4 elems same d
    const int e0 = wb & 63;
    float sv[4] = {s.x, s.y, s.z, s.w};
#pragma unroll
    for (int j = 0; j < 4; j++) {
      const int e = e0 + j;
      const unsigned short hi = f2bf(sv[j]);
      const unsigned short lo = f2bf(sv[j] - bf2f(hi));
      const int key = (e & 7) << 4;
      *(unsigned short*)(Bl + e * 256 + ((2 * d) ^ key))       = hi;
      *(unsigned short*)(Bl + e * 256 + ((128 + 2 * d) ^ key)) = lo;
    }
  }
  if (tid < 64) {
    float s = 0.f;
#pragma unroll
    for (int c = 0; c < NCHUNK; c++) s += ksp[((long)c * NHG + hg) * 64 + tid];
    const unsigned short hi = f2bf(s);
    const unsigned short lo = f2bf(s - bf2f(hi));
    *(unsigned short*)(Bl + 64 * 256 + 2 * tid)       = hi;   // row 64: key=0
    *(unsigned short*)(Bl + 64 * 256 + 128 + 2 * tid) = lo;
  }
  {  // zero rows 65..79
    uint32_t* zb = (uint32_t*)(Bl + 65 * 256);
    for (int i = tid; i < 15 * 64; i += 256) zb[i] = 0u;
  }
  __syncthreads();

  // ---- MFMA: per wave 64 l-rows x 80 cols, logical K=128 (hi pass + lo pass)
  const int wl0 = wid * 64;
  const int akey = (col16 & 7) << 4;

  bf16x8 af[4][2];
#pragma unroll
  for (int mi = 0; mi < 4; mi++)
#pragma unroll
    for (int ks = 0; ks < 2; ks++)
      af[mi][ks] = *(const bf16x8*)(smem + (wl0 + mi * 16 + col16) * 128 +
                                    ((ks * 64 + quad * 16) ^ akey));

  const f32x4 fzero = {0.f, 0.f, 0.f, 0.f};
  f32x4 acc[4][5];
#pragma unroll
  for (int mi = 0; mi < 4; mi++)
#pragma unroll
    for (int nf = 0; nf < 5; nf++) acc[mi][nf] = fzero;

#pragma unroll
  for (int nf = 0; nf < 5; nf++) {
    bf16x8 bfr[4];
#pragma unroll
    for (int pass = 0; pass < 2; pass++)
#pragma unroll
      for (int ks = 0; ks < 2; ks++)
        bfr[pass * 2 + ks] = *(const bf16x8*)(Bl + (nf * 16 + col16) * 256 +
                                              ((pass * 128 + ks * 64 + quad * 16) ^ akey));
#pragma unroll
    for (int mi = 0; mi < 4; mi++)
#pragma unroll
      for (int pass = 0; pass < 2; pass++)
#pragma unroll
        for (int ks = 0; ks < 2; ks++)
          acc[mi][nf] = __builtin_amdgcn_mfma_f32_16x16x32_bf16(
              af[mi][ks], bfr[pass * 2 + ks], acc[mi][nf], 0, 0, 0);
  }

  __syncthreads();   // all A reads done; reuse A region as epilogue buffer

  // ---- epilogue: z from denom col (lane quad*16 holds col 64), swizzled LDS
  unsigned short* epi = (unsigned short*)smem;
#pragma unroll
  for (int mi = 0; mi < 4; mi++) {
#pragma unroll
    for (int rr = 0; rr < 4; rr++) {
      const float dv = __shfl(acc[mi][4][rr], lane & 48);
      const float z = 1.f / (dv + 1e-6f);
      const int row = wl0 + mi * 16 + quad * 4 + rr;
      const int key = (row & 7) << 4;
#pragma unroll
      for (int nf = 0; nf < 4; nf++)
        *(unsigned short*)((char*)epi + row * 128 +
                           (((nf * 16 + col16) * 2) ^ key)) =
            f2bf(acc[mi][nf][rr] * z);
    }
  }
  __syncthreads();

  // packed readback: thread -> one row chunk of 16 B per pass, 8 passes
#pragma unroll
  for (int r = 0; r < 8; r++) {
    const int row = r * 32 + (tid >> 3);
    const long l = lbase + row;
    const uint4 vv = *(const uint4*)((char*)epi + row * 128 +
                                     (((tid & 7) * 16) ^ ((row & 7) << 4)));
    *(uint4*)(out1 + (l * NBATCH + n) * (long)EMB + h * HDIM + (tid & 7) * 8) = vv;
  }
}

// ---------------------------------------------------------------------------
extern "C" void kernel_launch(void* const* d_in, const int* in_sizes, int n_in,
                              void* d_out, int out_size, void* d_ws, size_t ws_size,
                              hipStream_t stream) {
  const float* q  = (const float*)d_in[0];
  const float* k  = (const float*)d_in[1];
  const float* v  = (const float*)d_in[2];
  const float* Wq = (const float*)d_in[3];
  const float* bq = (const float*)d_in[4];
  const float* Wk = (const float*)d_in[5];
  const float* bk = (const float*)d_in[6];
  const float* Wv = (const float*)d_in[7];
  const float* bv = (const float*)d_in[8];
  const float* Wo = (const float*)d_in[9];
  const float* bo = (const float*)d_in[10];

  char* ws = (char*)d_ws;
  const size_t BUF = (size_t)MROWS * EMB * 2;  // 33,554,432 B
  unsigned short* T0  = (unsigned short*)(ws);              // A-staging / out1
  unsigned short* qf  = (unsigned short*)(ws + BUF);
  unsigned short* kf  = (unsigned short*)(ws + 2 * BUF);
  unsigned short* vp  = (unsigned short*)(ws + 3 * BUF);
  unsigned short* Wqb = (unsigned short*)(ws + 4 * BUF);
  unsigned short* Wkb = Wqb + (size_t)EMB * EMB;
  unsigned short* Wvb = Wkb + (size_t)EMB * EMB;
  unsigned short* Wob = Wvb + (size_t)EMB * EMB;
  float* kvp = (float*)(ws + 4 * BUF + 4 * (size_t)EMB * EMB * 2);
  float* ksp = kvp + (size_t)NCHUNK * NHG * HDIM * HDIM;

  const int nQKV = MROWS * EMB;     // 16,777,216
  const int nW   = EMB * EMB;       // 1,048,576

  // all 4 weight matrices -> bf16 in one dispatch
  convert_w4<<<dim3(nW / 1024, 4), 256, 0, stream>>>(Wq, Wk, Wv, Wo,
                                                     Wqb, Wkb, Wvb, Wob, nW);

  dim3 gg(MROWS / 256, EMB / 256), bb(512);

  // projections (T0 reused as bf16 A-staging between GEMMs; stream-ordered,
  // interleaved convert->gemm keeps each A-buffer L3-hot at its consumer)
  convert_kernel<<<nQKV / 1024, 256, 0, stream>>>(q, T0, nQKV);
  gemm_bt<0><<<gg, bb, 0, stream>>>(T0, Wqb, bq, qf, MROWS, EMB, EMB);
  convert_kernel<<<nQKV / 1024, 256, 0, stream>>>(k, T0, nQKV);
  gemm_bt<0><<<gg, bb, 0, stream>>>(T0, Wkb, bk, kf, MROWS, EMB, EMB);
  convert_kernel<<<nQKV / 1024, 256, 0, stream>>>(v, T0, nQKV);
  gemm_bt<1><<<gg, bb, 0, stream>>>(T0, Wvb, bv, vp, MROWS, EMB, EMB);

  // attention state + output (out1 -> T0)
  kv_partial_kernel<<<dim3(NHG, NCHUNK), 256, 0, stream>>>(kf, vp, kvp, ksp);
  attn_out_kernel<<<dim3(NHG, L_SEQ / 256), 256, 0, stream>>>(qf, kvp, ksp, T0);

  // final projection -> fp32 output
  gemm_bt<2><<<gg, bb, 0, stream>>>(T0, Wob, bo, d_out, MROWS, EMB, EMB);
}

// Round 12
// 436.571 us; speedup vs baseline: 1.0626x; 1.0021x over previous
//
#include <hip/hip_runtime.h>
#include <hip/hip_bf16.h>
#include <cstdint>

// ---------------------------------------------------------------------------
// LinearAttention on MI355X (gfx950)
// L=4096, N=4, E=1024, H=16, D=64.  M = L*N = 16384.
// Round 16: cut GEMM barrier count 8 -> 5 per K-tile. Diagnosis: at 1
// block/CU, 8 lockstep-wave barriers/tile put us at ~6900 cyc/tile vs
// m201's ~3300 on the same structure; MFMA work is only ~620 cyc/tile and
// HBM 22% -> barrier-bound. Merge: ph0 {A-lo frags + ALL B frags (16
// ds_read); stage A-hi,B-hi(u+1); sync; 32 MFMA}, ph1 {A-hi frags; stage
// B-lo(u+2); sync; 32 MFMA}, ph2 {stage A-lo(u+2); boundary vmcnt; barrier}.
// Stage->slot stream, issue order and vmcnt(4) ledger are bit-identical to
// R11 (verified). A-lo(u+2) keeps its own micro-phase because A-slot SA is
// read in ph0 AND ph1 -- its write may only issue after a barrier following
// all readers' lgkmcnt drains (same WAR discipline as R4/R11).
// kv_partial (R11 MFMA), attn_out (R7 MFMA), converts unchanged.
// ---------------------------------------------------------------------------

typedef __attribute__((ext_vector_type(8))) short bf16x8;
typedef __attribute__((ext_vector_type(4))) float f32x4;

#define L_SEQ 4096
#define NBATCH 4
#define EMB 1024
#define NHEADS 16
#define HDIM 64
#define MROWS (L_SEQ * NBATCH)   // 16384
#define NHG (NBATCH * NHEADS)    // 64 head-groups
#define LCHUNK 512
#define NCHUNK (L_SEQ / LCHUNK)  // 8
#define KTS 72                   // kv_partial LDS l-stride (shorts)

__device__ __forceinline__ unsigned short f2bf(float f) {
  union { float f; uint32_t u; } v; v.f = f;
  uint32_t u = v.u;
  u += 0x7fffu + ((u >> 16) & 1u);   // round-to-nearest-even
  return (unsigned short)(u >> 16);
}
__device__ __forceinline__ float bf2f(unsigned short s) {
  union { uint32_t u; float f; } v; v.u = ((uint32_t)s) << 16;
  return v.f;
}
__device__ __forceinline__ uint32_t pkbf(float a, float b) {
  union { float f; uint32_t u; } ua, ub; ua.f = a; ub.f = b;
  return ((ua.u + 0x8000u) >> 16) | ((ub.u + 0x8000u) & 0xffff0000u);
}

// ---------------- fp32 -> bf16 convert ---------------------------------------
__global__ __launch_bounds__(256) void convert_kernel(const float* __restrict__ src,
                                                      unsigned short* __restrict__ dst,
                                                      int n) {
  int i = (blockIdx.x * 256 + threadIdx.x) * 4;
  if (i + 4 <= n) {
    float4 f = *(const float4*)(src + i);
    uint2 p;
    p.x = pkbf(f.x, f.y);
    p.y = pkbf(f.z, f.w);
    *(uint2*)(dst + i) = p;
  }
}

// ---------------- fp32 -> bf16 convert, 4 weight matrices -------------------
__global__ __launch_bounds__(256) void convert_w4(const float* __restrict__ s0,
                                                  const float* __restrict__ s1,
                                                  const float* __restrict__ s2,
                                                  const float* __restrict__ s3,
                                                  unsigned short* __restrict__ d0,
                                                  unsigned short* __restrict__ d1,
                                                  unsigned short* __restrict__ d2,
                                                  unsigned short* __restrict__ d3,
                                                  int n) {
  const int w = blockIdx.y;
  const float* src = (w == 0) ? s0 : (w == 1) ? s1 : (w == 2) ? s2 : s3;
  unsigned short* dst = (w == 0) ? d0 : (w == 1) ? d1 : (w == 2) ? d2 : d3;
  int i = (blockIdx.x * 256 + threadIdx.x) * 4;
  if (i + 4 <= n) {
    float4 f = *(const float4*)(src + i);
    uint2 p;
    p.x = pkbf(f.x, f.y);
    p.y = pkbf(f.z, f.w);
    *(uint2*)(dst + i) = p;
  }
}

// ---------------- bf16 MFMA GEMM: C = A(MxK) . B(NnxK)^T + bias -------------
// MODE 0: elu(x)+1 -> bf16 ; MODE 1: x -> bf16 ; MODE 2: x -> fp32
// M % 256 == 0, Nn % 256 == 0, K % 128 == 0 (NT = K/64 even, >= 4).
// 512 threads (8 waves: wr = wid>>2 in {0,1} -> M; wc = wid&3 -> N).
// LDS: A half-slots s*16384 (s=0..3), B half-slots 65536 + s*16384 (128 KB).
// Half-tile (128 rows x 64 k) of tile u, half h lives in slot (2u+h)&3.
// Swizzle: within a 128 B row, byte ^= ((row&7)<<4) (involution; applied to
// the gload_lds GLOBAL source and to ds_read addresses; LDS dest stays linear).

// stage one 128x64 half-tile: MATB 0=A/1=B, RH row-half, SLOT, KTN k-offset.
#define STAGE_H(MATB, RH, SLOT, KTN)                                            \
  do {                                                                          \
    _Pragma("unroll")                                                           \
    for (int r_ = 0; r_ < 2; r_++) {                                            \
      const long grow_ = ((MATB) ? bcol0 : arow0) + (RH) * 128 + r_ * 64 + srowt;\
      const unsigned short* gp_ =                                               \
          ((MATB) ? B : A) + grow_ * (long)K + (KTN) + skoff;                   \
      __builtin_amdgcn_global_load_lds(                                         \
          (const __attribute__((address_space(1))) void*)gp_,                   \
          (__attribute__((address_space(3))) void*)(smem + (MATB) * 65536 +     \
              (SLOT) * 16384 + r_ * 8192 + wid * 1024),                         \
          16, 0, 0);                                                            \
    }                                                                           \
  } while (0)

// one 32-MFMA cluster: C quadrant rows MFB..MFB+3 x ALL 4 N-frags, K=64
#define MFMA_H(AF, MFB)                                                         \
  do {                                                                          \
    __builtin_amdgcn_s_setprio(1);                                              \
    _Pragma("unroll")                                                           \
    for (int mi_ = 0; mi_ < 4; mi_++)                                           \
      _Pragma("unroll")                                                         \
      for (int nf_ = 0; nf_ < 4; nf_++)                                         \
        _Pragma("unroll")                                                       \
        for (int ks_ = 0; ks_ < 2; ks_++)                                       \
          acc[(MFB) + mi_][nf_] =                                               \
              __builtin_amdgcn_mfma_f32_16x16x32_bf16(                          \
                  AF[mi_ * 2 + ks_], bfr[nf_ * 2 + ks_],                        \
                  acc[(MFB) + mi_][nf_], 0, 0, 0);                              \
    __builtin_amdgcn_s_setprio(0);                                              \
  } while (0)

#define PH_SYNC                                                                 \
  __builtin_amdgcn_s_barrier();                                                 \
  asm volatile("s_waitcnt lgkmcnt(0)" ::: "memory");                            \
  __builtin_amdgcn_sched_barrier(0);

// one K-tile u (A/B lo slots at SA, hi at SA+1; SA in {0,2} = (2u)&3).
// ph0: read A rows 0-63 (wave's slot SA+wr) + ALL B frags; stage A-hi(u+1),
//      B-hi(u+1) -> SA^3 (iff S01); sync; 32 MFMA; barrier.
// ph1: read A rows 64-127; stage B-lo(u+2) -> SA (B-slot reads drained at
//      end-ph0 barrier) (iff S23); sync; 32 MFMA; barrier.
// ph2: stage A-lo(u+2) -> SA (A-slot reads drained at end-ph1 barrier)
//      (iff S23); boundary wait; barrier.
// VMODE: 1 = vmcnt(4) (steady), 2 = vmcnt(0) (tail fill), 0 = none.
#define TILE_T(SA, K1, K2, S01, S23, VMODE)                                     \
  do {                                                                          \
    bf16x8 af0[8], af1[8], bfr[8];                                              \
    /* ph0 */                                                                   \
    _Pragma("unroll")                                                           \
    for (int mi_ = 0; mi_ < 4; mi_++)                                           \
      _Pragma("unroll")                                                         \
      for (int ks_ = 0; ks_ < 2; ks_++)                                         \
        af0[mi_ * 2 + ks_] = *(const bf16x8*)(smem + ((SA) + wr) * 16384 + aRB +\
                                              mi_ * 2048 + akt[ks_]);           \
    _Pragma("unroll")                                                           \
    for (int ni_ = 0; ni_ < 4; ni_++)                                           \
      _Pragma("unroll")                                                         \
      for (int ks_ = 0; ks_ < 2; ks_++)                                         \
        bfr[ni_ * 2 + ks_] = *(const bf16x8*)(smem + 65536 +                    \
                                              ((SA) + (wc >> 1)) * 16384 + bRB +\
                                              ni_ * 2048 + akt[ks_]);           \
    if (S01) { STAGE_H(0, 1, (SA) ^ 3, K1); STAGE_H(1, 1, (SA) ^ 3, K1); }      \
    PH_SYNC                                                                     \
    MFMA_H(af0, 0);                                                             \
    __builtin_amdgcn_s_barrier();                                               \
    /* ph1 */                                                                   \
    _Pragma("unroll")                                                           \
    for (int mi_ = 0; mi_ < 4; mi_++)                                           \
      _Pragma("unroll")                                                         \
      for (int ks_ = 0; ks_ < 2; ks_++)                                         \
        af1[mi_ * 2 + ks_] = *(const bf16x8*)(smem + ((SA) + wr) * 16384 + aRB +\
                                              (mi_ + 4) * 2048 + akt[ks_]);     \
    if (S23) STAGE_H(1, 0, (SA), K2);                                           \
    PH_SYNC                                                                     \
    MFMA_H(af1, 4);                                                             \
    __builtin_amdgcn_s_barrier();                                               \
    /* ph2: stage-only micro-phase + boundary */                                \
    if (S23) STAGE_H(0, 0, (SA), K2);                                           \
    if ((VMODE) == 1) asm volatile("s_waitcnt vmcnt(4)" ::: "memory");          \
    if ((VMODE) == 2) asm volatile("s_waitcnt vmcnt(0)" ::: "memory");          \
    __builtin_amdgcn_s_barrier();                                               \
  } while (0)

template <int MODE>
__global__ __launch_bounds__(512, 2) void gemm_bt(const unsigned short* __restrict__ A,
                                                  const unsigned short* __restrict__ B,
                                                  const float* __restrict__ bias,
                                                  void* __restrict__ Cout,
                                                  int M, int Nn, int K) {
  __shared__ __align__(16) char smem[131072];

  const int tid   = threadIdx.x;
  const int wid   = tid >> 6;
  const int lane  = tid & 63;
  const int col16 = lane & 15;
  const int quad  = lane >> 4;
  const int wr = wid >> 2;       // 0..1 : M half (rows wr*128..+127)
  const int wc = wid & 3;        // 0..3 : N quarter (cols wc*64..+63)
  const long arow0 = (long)blockIdx.x * 256;
  const long bcol0 = (long)blockIdx.y * 256;

  // ---- read-address constants (swizzled) ----
  const int axor = (col16 & 7) << 4;
  int akt[2];
  akt[0] = (quad * 16) ^ axor;
  akt[1] = (64 + quad * 16) ^ axor;
  const int aRB = col16 * 128;                    // within-slot A row base
  const int bRB = ((wc & 1) * 64 + col16) * 128;  // within-slot B row base

  // ---- staging constants (inverse-swizzled global source) ----
  const int srowt = tid >> 3;                                   // 0..63
  const int skoff = (((tid & 7) * 16) ^ ((srowt & 7) << 4)) >> 1;  // shorts

  const int NT = K >> 6;   // K-tiles of 64 (even, >= 4)

  // prologue: tile0 all 4 halves + B-lo(1) + A-lo(1)  (6 stage-ops, 12 loads)
  STAGE_H(0, 0, 0, 0);      // A-lo(0) -> A-slot0
  STAGE_H(0, 1, 1, 0);      // A-hi(0) -> A-slot1
  STAGE_H(1, 0, 0, 0);      // B-lo(0) -> B-slot0
  STAGE_H(1, 1, 1, 0);      // B-hi(0) -> B-slot1
  STAGE_H(1, 0, 2, 64);     // B-lo(1) -> B-slot2
  STAGE_H(0, 0, 2, 64);     // A-lo(1) -> A-slot2

  const f32x4 fzero = {0.f, 0.f, 0.f, 0.f};
  f32x4 acc[8][4];
#pragma unroll
  for (int i = 0; i < 8; i++)
#pragma unroll
    for (int j = 0; j < 4; j++) acc[i][j] = fzero;

  asm volatile("s_waitcnt vmcnt(4)" ::: "memory");  // tile 0 resident
  __builtin_amdgcn_s_barrier();

  // main loop: full-stage tiles 0..NT-3 in pairs
#pragma unroll 1
  for (int u = 0; u + 4 <= NT; u += 2) {
    TILE_T(0, (u + 1) * 64, (u + 2) * 64, 1, 1, 1);
    TILE_T(2, (u + 2) * 64, (u + 3) * 64, 1, 1, 1);
  }
  // tail: tile NT-2 stages only hi-halves of NT-1; tile NT-1 stages nothing
  TILE_T(0, (NT - 1) * 64, 0, 1, 0, 2);
  TILE_T(2, 0, 0, 0, 0, 0);

  // ---- epilogue: 8 slabs of 32 rows x 256 cols through LDS ----
  // C/D frag: row = quad*4 + rr, col = col16 (verified layout).
  float bcol[4];
#pragma unroll
  for (int nf = 0; nf < 4; nf++) bcol[nf] = bias[bcol0 + wc * 64 + nf * 16 + col16];

  const int erow = tid >> 4;   // 0..31
  const int ecc  = tid & 15;   // 16-col chunk

  if (MODE != 2) {
    unsigned short* epi = (unsigned short*)smem;
    const int EST = 264;  // shorts; 528 B row stride (16B-aligned, bank-skewed)
#pragma unroll
    for (int s = 0; s < 8; s++) {
      if ((s >> 2) == wr) {
        const int mfb = (s & 3) * 2;
#pragma unroll
        for (int ml = 0; ml < 2; ml++)
#pragma unroll
          for (int nf = 0; nf < 4; nf++)
#pragma unroll
            for (int rr = 0; rr < 4; rr++) {
              float vv = acc[mfb + ml][nf][rr] + bcol[nf];
              if (MODE == 0) vv = (vv > 0.f) ? (vv + 1.f) : __expf(vv);  // elu+1
              epi[(ml * 16 + quad * 4 + rr) * EST + wc * 64 + nf * 16 + col16] =
                  f2bf(vv);
            }
      }
      __syncthreads();
      {
        const long gr = arow0 + s * 32 + erow;
        const unsigned short* srcp = &epi[erow * EST + ecc * 16];
        uint4 a  = *(const uint4*)srcp;
        uint4 b2 = *(const uint4*)(srcp + 8);
        unsigned short* Cp = (unsigned short*)Cout + gr * Nn + bcol0 + ecc * 16;
        *(uint4*)Cp       = a;
        *(uint4*)(Cp + 8) = b2;
      }
      __syncthreads();
    }
  } else {
    float* epi = (float*)smem;
    const int ESF = 260;  // floats; 1040 B row stride (16B-aligned, bank-skewed)
#pragma unroll
    for (int s = 0; s < 8; s++) {
      if ((s >> 2) == wr) {
        const int mfb = (s & 3) * 2;
#pragma unroll
        for (int ml = 0; ml < 2; ml++)
#pragma unroll
          for (int nf = 0; nf < 4; nf++)
#pragma unroll
            for (int rr = 0; rr < 4; rr++)
              epi[(ml * 16 + quad * 4 + rr) * ESF + wc * 64 + nf * 16 + col16] =
                  acc[mfb + ml][nf][rr] + bcol[nf];
      }
      __syncthreads();
      {
        const long gr = arow0 + s * 32 + erow;
        const float* srcp = &epi[erow * ESF + ecc * 16];
        float* Cp = (float*)Cout + gr * Nn + bcol0 + ecc * 16;
#pragma unroll
        for (int s4 = 0; s4 < 4; s4++)
          *(float4*)(Cp + s4 * 4) = *(const float4*)(srcp + s4 * 4);
      }
      __syncthreads();
    }
  }
}

// ---------------- kv partials via MFMA --------------------------------------
// kv[d][e] = sum_l kf[l][d]*v[l][e]; ksum[d] = sum_l kf[l][d].
// grid (NHG, NCHUNK), block 256 (4 waves). Wave w computes d-band w*16..+15
// x 80 cols: e 0..63 = kv, col 64 = ksum (ones-column), 65..79 discarded.
// LDS: ks_t [64 d][KTS l] bf16, vs_t [80 e][KTS l] bf16 (transposed staging;
// KTS=72 shorts keeps b128 rows 16B-aligned; read conflicts <=2-way).
__global__ __launch_bounds__(256) void kv_partial_kernel(const unsigned short* __restrict__ kf,
                                                         const unsigned short* __restrict__ vp,
                                                         float* __restrict__ kvp,
                                                         float* __restrict__ ksp) {
  __shared__ __align__(16) unsigned short ks_t[64 * KTS];
  __shared__ __align__(16) unsigned short vs_t[80 * KTS];
  const int hg = blockIdx.x;
  const int chunk = blockIdx.y;
  const int n = hg >> 4, h = hg & 15;
  const int tid = threadIdx.x;
  const int wid = tid >> 6;
  const int lane = tid & 63;
  const int col16 = lane & 15;
  const int quad  = lane >> 4;
  const long hoff = (long)n * EMB + h * HDIM;
  const int l0 = chunk * LCHUNK;

  // staging assignment: thread covers l = tid>>2 (0..63), d0 = (tid&3)*16
  const int sl  = tid >> 2;
  const int sd0 = (tid & 3) * 16;

  // init B rows 64..79: row 64 = 1.0 (ksum column), rows 65..79 = 0
  for (int i = tid; i < 16 * KTS; i += 256)
    vs_t[64 * KTS + i] = (i < KTS) ? (unsigned short)0x3F80u : (unsigned short)0u;

  const f32x4 fzero = {0.f, 0.f, 0.f, 0.f};
  f32x4 acc[5];
#pragma unroll
  for (int nf = 0; nf < 5; nf++) acc[nf] = fzero;

  for (int ls = 0; ls < LCHUNK; ls += 64) {
    // issue global loads (16 bf16 of kf + 16 of v for one l) before barrier
    const long g = (long)(l0 + ls + sl) * (NBATCH * EMB) + hoff + sd0;
    uint4 kr0 = *(const uint4*)(kf + g);
    uint4 kr1 = *(const uint4*)(kf + g + 8);
    uint4 vr0 = *(const uint4*)(vp + g);
    uint4 vr1 = *(const uint4*)(vp + g + 8);
    __syncthreads();   // previous slab's fragment reads complete
    {
      uint32_t ku[8] = {kr0.x, kr0.y, kr0.z, kr0.w, kr1.x, kr1.y, kr1.z, kr1.w};
      uint32_t vu[8] = {vr0.x, vr0.y, vr0.z, vr0.w, vr1.x, vr1.y, vr1.z, vr1.w};
#pragma unroll
      for (int t = 0; t < 8; t++) {
        ks_t[(sd0 + 2 * t)     * KTS + sl] = (unsigned short)(ku[t] & 0xffffu);
        ks_t[(sd0 + 2 * t + 1) * KTS + sl] = (unsigned short)(ku[t] >> 16);
        vs_t[(sd0 + 2 * t)     * KTS + sl] = (unsigned short)(vu[t] & 0xffffu);
        vs_t[(sd0 + 2 * t + 1) * KTS + sl] = (unsigned short)(vu[t] >> 16);
      }
    }
    __syncthreads();   // slab resident
#pragma unroll
    for (int kk = 0; kk < 2; kk++) {
      const bf16x8 af =
          *(const bf16x8*)(&ks_t[(wid * 16 + col16) * KTS + kk * 32 + quad * 8]);
#pragma unroll
      for (int nf = 0; nf < 5; nf++) {
        const bf16x8 bfv =
            *(const bf16x8*)(&vs_t[(nf * 16 + col16) * KTS + kk * 32 + quad * 8]);
        acc[nf] = __builtin_amdgcn_mfma_f32_16x16x32_bf16(af, bfv, acc[nf], 0, 0, 0);
      }
    }
  }

  // write partials: C row (d) = wid*16 + quad*4 + rr, col (e) = nf*16 + col16
  float* outp = kvp + ((long)chunk * NHG + hg) * 4096;
  const int dr = wid * 16 + quad * 4;
#pragma unroll
  for (int nf = 0; nf < 4; nf++)
#pragma unroll
    for (int rr = 0; rr < 4; rr++)
      outp[(dr + rr) * 64 + nf * 16 + col16] = acc[nf][rr];
  if (col16 == 0) {
    float* o2 = ksp + ((long)chunk * NHG + hg) * 64;
#pragma unroll
    for (int rr = 0; rr < 4; rr++) o2[dr + rr] = acc[4][rr];
  }
}

// ---------------- out1 = (qf @ kv) * 1/(qf.ksum + eps), bf16 row-major ------
// grid (NHG, 16), block 256 (4 waves). MFMA version; kvp reduce
// float4-vectorized.
__global__ __launch_bounds__(256) void attn_out_kernel(const unsigned short* __restrict__ qf,
                                                       const float* __restrict__ kvp,
                                                       const float* __restrict__ ksp,
                                                       unsigned short* __restrict__ out1) {
  __shared__ __align__(16) char smem[53248];
  const int hg = blockIdx.x;
  const int lc = blockIdx.y;
  const int n = hg >> 4, h = hg & 15;
  const int tid = threadIdx.x;
  const int wid = tid >> 6;
  const int lane = tid & 63;
  const int col16 = lane & 15;
  const int quad  = lane >> 4;
  const long lbase = (long)lc * 256;

  // ---- stage A = qf[lbase..+255][h*64..+63] via gload_lds (swizzled source)
#pragma unroll
  for (int r = 0; r < 8; r++) {
    const int row = r * 32 + (tid >> 3);
    const long l = lbase + row;
    const int sk = (((tid & 7) * 16) ^ ((row & 7) << 4)) >> 1;   // shorts
    const unsigned short* gp = qf + (l * NBATCH + n) * (long)EMB + h * HDIM + sk;
    __builtin_amdgcn_global_load_lds(
        (const __attribute__((address_space(1))) void*)gp,
        (__attribute__((address_space(3))) void*)(smem + r * 4096 + tid * 16),
        16, 0, 0);
  }

  // ---- build B: reduce kv partials (float4 loads), hi/lo split, transposed
  //      swizzled writes
  char* Bl = smem + 32768;
  for (int wb = tid * 4; wb < 4096; wb += 1024) {
    float4 s = make_float4(0.f, 0.f, 0.f, 0.f);
#pragma unroll
    for (int c = 0; c < NCHUNK; c++) {
      const float4 t = *(const float4*)(kvp + ((long)c * NHG + hg) * 4096 + wb);
      s.x += t.x; s.y += t.y; s.z += t.z; s.w += t.w;
    }
    const int d = wb >> 6;      // wb%64 in {0,4,..,60}: all 4 elems same d
    const int e0 = wb & 63;
    float sv[4] = {s.x, s.y, s.z, s.w};
#pragma unroll
    for (int j = 0; j < 4; j++) {
      const int e = e0 + j;
      const unsigned short hi = f2bf(sv[j]);
      const unsigned short lo = f2bf(sv[j] - bf2f(hi));
      const int key = (e & 7) << 4;
      *(unsigned short*)(Bl + e * 256 + ((2 * d) ^ key))       = hi;
      *(unsigned short*)(Bl + e * 256 + ((128 + 2 * d) ^ key)) = lo;
    }
  }
  if (tid < 64) {
    float s = 0.f;
#pragma unroll
    for (int c = 0; c < NCHUNK; c++) s += ksp[((long)c * NHG + hg) * 64 + tid];
    const unsigned short hi = f2bf(s);
    const unsigned short lo = f2bf(s - bf2f(hi));
    *(unsigned short*)(Bl + 64 * 256 + 2 * tid)       = hi;   // row 64: key=0
    *(unsigned short*)(Bl + 64 * 256 + 128 + 2 * tid) = lo;
  }
  {  // zero rows 65..79
    uint32_t* zb = (uint32_t*)(Bl + 65 * 256);
    for (int i = tid; i < 15 * 64; i += 256) zb[i] = 0u;
  }
  __syncthreads();

  // ---- MFMA: per wave 64 l-rows x 80 cols, logical K=128 (hi pass + lo pass)
  const int wl0 = wid * 64;
  const int akey = (col16 & 7) << 4;

  bf16x8 af[4][2];
#pragma unroll
  for (int mi = 0; mi < 4; mi++)
#pragma unroll
    for (int ks = 0; ks < 2; ks++)
      af[mi][ks] = *(const bf16x8*)(smem + (wl0 + mi * 16 + col16) * 128 +
                                    ((ks * 64 + quad * 16) ^ akey));

  const f32x4 fzero = {0.f, 0.f, 0.f, 0.f};
  f32x4 acc[4][5];
#pragma unroll
  for (int mi = 0; mi < 4; mi++)
#pragma unroll
    for (int nf = 0; nf < 5; nf++) acc[mi][nf] = fzero;

#pragma unroll
  for (int nf = 0; nf < 5; nf++) {
    bf16x8 bfr[4];
#pragma unroll
    for (int pass = 0; pass < 2; pass++)
#pragma unroll
      for (int ks = 0; ks < 2; ks++)
        bfr[pass * 2 + ks] = *(const bf16x8*)(Bl + (nf * 16 + col16) * 256 +
                                              ((pass * 128 + ks * 64 + quad * 16) ^ akey));
#pragma unroll
    for (int mi = 0; mi < 4; mi++)
#pragma unroll
      for (int pass = 0; pass < 2; pass++)
#pragma unroll
        for (int ks = 0; ks < 2; ks++)
          acc[mi][nf] = __builtin_amdgcn_mfma_f32_16x16x32_bf16(
              af[mi][ks], bfr[pass * 2 + ks], acc[mi][nf], 0, 0, 0);
  }

  __syncthreads();   // all A reads done; reuse A region as epilogue buffer

  // ---- epilogue: z from denom col (lane quad*16 holds col 64), swizzled LDS
  unsigned short* epi = (unsigned short*)smem;
#pragma unroll
  for (int mi = 0; mi < 4; mi++) {
#pragma unroll
    for (int rr = 0; rr < 4; rr++) {
      const float dv = __shfl(acc[mi][4][rr], lane & 48);
      const float z = 1.f / (dv + 1e-6f);
      const int row = wl0 + mi * 16 + quad * 4 + rr;
      const int key = (row & 7) << 4;
#pragma unroll
      for (int nf = 0; nf < 4; nf++)
        *(unsigned short*)((char*)epi + row * 128 +
                           (((nf * 16 + col16) * 2) ^ key)) =
            f2bf(acc[mi][nf][rr] * z);
    }
  }
  __syncthreads();

  // packed readback: thread -> one row chunk of 16 B per pass, 8 passes
#pragma unroll
  for (int r = 0; r < 8; r++) {
    const int row = r * 32 + (tid >> 3);
    const long l = lbase + row;
    const uint4 vv = *(const uint4*)((char*)epi + row * 128 +
                                     (((tid & 7) * 16) ^ ((row & 7) << 4)));
    *(uint4*)(out1 + (l * NBATCH + n) * (long)EMB + h * HDIM + (tid & 7) * 8) = vv;
  }
}

// ---------------------------------------------------------------------------
extern "C" void kernel_launch(void* const* d_in, const int* in_sizes, int n_in,
                              void* d_out, int out_size, void* d_ws, size_t ws_size,
                              hipStream_t stream) {
  const float* q  = (const float*)d_in[0];
  const float* k  = (const float*)d_in[1];
  const float* v  = (const float*)d_in[2];
  const float* Wq = (const float*)d_in[3];
  const float* bq = (const float*)d_in[4];
  const float* Wk = (const float*)d_in[5];
  const float* bk = (const float*)d_in[6];
  const float* Wv = (const float*)d_in[7];
  const float* bv = (const float*)d_in[8];
  const float* Wo = (const float*)d_in[9];
  const float* bo = (const float*)d_in[10];

  char* ws = (char*)d_ws;
  const size_t BUF = (size_t)MROWS * EMB * 2;  // 33,554,432 B
  unsigned short* T0  = (unsigned short*)(ws);              // A-staging / out1
  unsigned short* qf  = (unsigned short*)(ws + BUF);
  unsigned short* kf  = (unsigned short*)(ws + 2 * BUF);
  unsigned short* vp  = (unsigned short*)(ws + 3 * BUF);
  unsigned short* Wqb = (unsigned short*)(ws + 4 * BUF);
  unsigned short* Wkb = Wqb + (size_t)EMB * EMB;
  unsigned short* Wvb = Wkb + (size_t)EMB * EMB;
  unsigned short* Wob = Wvb + (size_t)EMB * EMB;
  float* kvp = (float*)(ws + 4 * BUF + 4 * (size_t)EMB * EMB * 2);
  float* ksp = kvp + (size_t)NCHUNK * NHG * HDIM * HDIM;

  const int nQKV = MROWS * EMB;     // 16,777,216
  const int nW   = EMB * EMB;       // 1,048,576

  // all 4 weight matrices -> bf16 in one dispatch
  convert_w4<<<dim3(nW / 1024, 4), 256, 0, stream>>>(Wq, Wk, Wv, Wo,
                                                     Wqb, Wkb, Wvb, Wob, nW);

  dim3 gg(MROWS / 256, EMB / 256), bb(512);

  // projections (T0 reused as bf16 A-staging between GEMMs; stream-ordered,
  // interleaved convert->gemm keeps each A-buffer L3-hot at its consumer)
  convert_kernel<<<nQKV / 1024, 256, 0, stream>>>(q, T0, nQKV);
  gemm_bt<0><<<gg, bb, 0, stream>>>(T0, Wqb, bq, qf, MROWS, EMB, EMB);
  convert_kernel<<<nQKV / 1024, 256, 0, stream>>>(k, T0, nQKV);
  gemm_bt<0><<<gg, bb, 0, stream>>>(T0, Wkb, bk, kf, MROWS, EMB, EMB);
  convert_kernel<<<nQKV / 1024, 256, 0, stream>>>(v, T0, nQKV);
  gemm_bt<1><<<gg, bb, 0, stream>>>(T0, Wvb, bv, vp, MROWS, EMB, EMB);

  // attention state + output (out1 -> T0)
  kv_partial_kernel<<<dim3(NHG, NCHUNK), 256, 0, stream>>>(kf, vp, kvp, ksp);
  attn_out_kernel<<<dim3(NHG, L_SEQ / 256), 256, 0, stream>>>(qf, kvp, ksp, T0);

  // final projection -> fp32 output
  gemm_bt<2><<<gg, bb, 0, stream>>>(T0, Wob, bo, d_out, MROWS, EMB, EMB);
}